// Round 9
// baseline (756.016 us; speedup 1.0000x reference)
//
#include <hip/hip_runtime.h>
#include <cstdint>
#include <cstddef>

namespace {

typedef unsigned short ushort_t;
typedef __bf16 bf16x8 __attribute__((ext_vector_type(8)));
typedef float  f32x4  __attribute__((ext_vector_type(4)));

constexpr int B_ = 4;
constexpr int N0 = 4096;   // vertices per batch
constexpr int N1 = 1024;   // after pool1
constexpr int N2 = 256;    // after pool2

// ----------------------------------------------------- bf16 split utils ----
__device__ __forceinline__ ushort_t f2bf_rne(float x) {
  uint32_t b = __float_as_uint(x);
  b += 0x7FFFu + ((b >> 16) & 1u);
  return (ushort_t)(b >> 16);
}
__device__ __forceinline__ float bf2f(ushort_t h) {
  return __uint_as_float(((uint32_t)h) << 16);
}
__device__ __forceinline__ void split_store(float x, ushort_t* hi, ushort_t* lo,
                                            size_t i) {
  const ushort_t h = f2bf_rne(x);
  hi[i] = h;
  lo[i] = f2bf_rne(x - bf2f(h));
}

// direct global->LDS DMA, 16 B per lane; dest = ldsbase + lane*16
__device__ __forceinline__ void async_copy16(const ushort_t* g, ushort_t* l) {
  __builtin_amdgcn_global_load_lds(
      (const __attribute__((address_space(1))) void*)g,
      (__attribute__((address_space(3))) void*)l, 16, 0, 0);
}

// --------------------------------------- fused weight prep (one dispatch) --
__global__ void weight_prep_kernel(
    const float* __restrict__ w1, const float* __restrict__ w2,
    const float* __restrict__ w3, const float* __restrict__ w4,
    const float* __restrict__ cw1, const float* __restrict__ cw2,
    ushort_t* __restrict__ w1th, ushort_t* __restrict__ w1tl,
    ushort_t* __restrict__ w2th, ushort_t* __restrict__ w2tl,
    ushort_t* __restrict__ w3th, ushort_t* __restrict__ w3tl,
    ushort_t* __restrict__ w4th, ushort_t* __restrict__ w4tl,
    ushort_t* __restrict__ w1h, ushort_t* __restrict__ w1l,
    ushort_t* __restrict__ w2h, ushort_t* __restrict__ w2l)
{
  const int i = blockIdx.x * blockDim.x + threadIdx.x;
  if (i < 32768) {                       // w1: K=128, N=256
    const int j = i, k = j % 128, n = j / 128;
    split_store(w1[(size_t)k * 256 + n], w1th, w1tl, (size_t)n * 128 + k);
  } else if (i < 98304) {                // w2: K=128, N=512
    const int j = i - 32768, k = j % 128, n = j / 128;
    split_store(w2[(size_t)k * 512 + n], w2th, w2tl, (size_t)n * 128 + k);
  } else if (i < 229376) {               // w3: K=256, N=512
    const int j = i - 98304, k = j % 256, n = j / 256;
    split_store(w3[(size_t)k * 512 + n], w3th, w3tl, (size_t)n * 256 + k);
  } else if (i < 491520) {               // w4: K=256, N=1024
    const int j = i - 229376, k = j % 256, n = j / 256;
    split_store(w4[(size_t)k * 1024 + n], w4th, w4tl, (size_t)n * 256 + k);
  } else if (i < 1409024) {              // cw1: already (N,K)
    const int j = i - 491520;
    split_store(cw1[j], w1h, w1l, j);
  } else if (i < 1671168) {              // cw2
    const int j = i - 1409024;
    split_store(cw2[j], w2h, w2l, j);
  }
}

// ------------------------------------------------- wave-cooperative KNN ----
__device__ __forceinline__ void bitonic_sort64(float& sd, int& si, int lane) {
#pragma unroll
  for (int kk = 2; kk <= 64; kk <<= 1) {
#pragma unroll
    for (int j = kk >> 1; j > 0; j >>= 1) {
      const float od = __shfl_xor(sd, j);
      const int   oi = __shfl_xor(si, j);
      const bool less    = (sd < od) || (sd == od && si < oi);
      const bool wantMin = ((lane & j) == 0) == ((lane & kk) == 0);
      if (wantMin != less) { sd = od; si = oi; }
    }
  }
}

__device__ __forceinline__ void knn_flush(float& ld, int& li, float& tau,
                                          int cnt, const float* bufd,
                                          const int* bufi, int lane, int Km1) {
  float sd = (lane < cnt) ? bufd[lane] : INFINITY;
  int   si = (lane < cnt) ? bufi[lane] : 0x7fffffff;
  bitonic_sort64(sd, si, lane);
  const float rd = __shfl(sd, 63 - lane);
  const int   ri = __shfl(si, 63 - lane);
  const bool keep = (ld < rd) || (ld == rd && li < ri);
  float md = keep ? ld : rd;
  int   mi = keep ? li : ri;
#pragma unroll
  for (int j = 32; j > 0; j >>= 1) {
    const float od = __shfl_xor(md, j);
    const int   oi = __shfl_xor(mi, j);
    const bool less    = (md < od) || (md == od && mi < oi);
    const bool wantMin = ((lane & j) == 0);
    if (wantMin != less) { md = od; mi = oi; }
  }
  ld = md; li = mi;
  tau = __shfl(ld, Km1);
}

// 16 waves/block (one query each); LDS tiles of (x,y,z,|p|^2) shared by all.
template<int K, int TILE>
__launch_bounds__(1024)
__global__ void knn_wave_kernel(const float* __restrict__ pts,   // (B, C, 3)
                                int Q, int C,
                                int* __restrict__ out)           // (B, Q, K)
{
  __shared__ float4 sp[TILE];
  __shared__ float sbd[16][64];
  __shared__ int   sbi[16][64];
  const int b    = blockIdx.y;
  const int lane = threadIdx.x & 63;
  const int wid  = threadIdx.x >> 6;
  const int q    = blockIdx.x * 16 + wid;
  const int self = q;
  const float* pb = pts + (size_t)b * C * 3;
  const float qx = pb[self * 3 + 0];
  const float qy = pb[self * 3 + 1];
  const float qz = pb[self * 3 + 2];
  const float q2   = qx * qx + qy * qy + qz * qz;
  const float m2qx = -2.0f * qx, m2qy = -2.0f * qy, m2qz = -2.0f * qz;

  float ld = INFINITY; int li = 0x7fffffff;
  float tau = INFINITY;
  int cnt = 0;
  float* bufd = sbd[wid];
  int*   bufi = sbi[wid];

  auto append = [&](unsigned long long m, bool cand, float d, int ci) {
    const int c = __popcll(m);
    if (cnt + c > 64) {
      knn_flush(ld, li, tau, cnt, bufd, bufi, lane, K - 1);
      cnt = 0;
    }
    const int prefix = __popcll(m & ((1ull << lane) - 1ull));
    if (cand) { bufd[cnt + prefix] = d; bufi[cnt + prefix] = ci; }
    cnt += c;
  };

  for (int t0 = 0; t0 < C; t0 += TILE) {
    __syncthreads();
    for (int i = threadIdx.x; i < TILE; i += 1024) {
      const float x = pb[(t0 + i) * 3 + 0];
      const float y = pb[(t0 + i) * 3 + 1];
      const float z = pb[(t0 + i) * 3 + 2];
      sp[i] = make_float4(x, y, z, x * x + y * y + z * z);
    }
    __syncthreads();
    int base = 0;
    if (t0 == 0) {
      const float4 p = sp[lane];
      const float d = fmaf(m2qx, p.x, fmaf(m2qy, p.y, fmaf(m2qz, p.z, p.w + q2)));
      const bool valid = (lane != self);
      float sd = valid ? d : INFINITY;
      int   si = valid ? lane : 0x7fffffff;
      bitonic_sort64(sd, si, lane);
      ld = sd; li = si;
      tau = __shfl(ld, K - 1);
      base = 64;
    }
    for (; base + 128 <= TILE; base += 128) {
      const int ci0 = t0 + base + lane;
      const int ci1 = ci0 + 64;
      const float4 p0 = sp[base + lane];
      const float4 p1 = sp[base + 64 + lane];
      const float d0 = fmaf(m2qx, p0.x, fmaf(m2qy, p0.y, fmaf(m2qz, p0.z, p0.w + q2)));
      const float d1 = fmaf(m2qx, p1.x, fmaf(m2qy, p1.y, fmaf(m2qz, p1.z, p1.w + q2)));
      const bool c0 = (ci0 != self) && (d0 < tau);
      const bool c1 = (ci1 != self) && (d1 < tau);
      const unsigned long long m0 = __ballot(c0);
      const unsigned long long m1 = __ballot(c1);
      if (m0) append(m0, c0, d0, ci0);
      if (m1) append(m1, c1, d1, ci1);
    }
    if (base < TILE) {                   // 64-tail (first tile only)
      const int ci = t0 + base + lane;
      const float4 p = sp[base + lane];
      const float d = fmaf(m2qx, p.x, fmaf(m2qy, p.y, fmaf(m2qz, p.z, p.w + q2)));
      const bool c = (ci != self) && (d < tau);
      const unsigned long long m = __ballot(c);
      if (m) append(m, c, d, ci);
    }
  }
  if (cnt > 0) knn_flush(ld, li, tau, cnt, bufd, bufi, lane, K - 1);
  if (lane < K) out[((size_t)b * Q + q) * K + lane] = li;
}

// -------------------------------------------- dual-level wave argmin -------
__launch_bounds__(256)
__global__ void nearest_dual_kernel(const float* __restrict__ qpts, // (B*N0,3)
                                    const float* __restrict__ cpts1,
                                    const float* __restrict__ cpts2,
                                    int* __restrict__ out1,
                                    int* __restrict__ out2)
{
  __shared__ float4 sp[1024];
  const int lvl = blockIdx.y;
  const int C = lvl ? N2 : N1;
  const float* cpts = lvl ? cpts2 : cpts1;
  int* out = lvl ? out2 : out1;
  const int lane = threadIdx.x & 63;
  const int wid  = threadIdx.x >> 6;
  const int q    = blockIdx.x * 4 + wid;        // over B_*N0
  const int b    = q >> 12;                     // / 4096
  const float qx = qpts[(size_t)q * 3 + 0];
  const float qy = qpts[(size_t)q * 3 + 1];
  const float qz = qpts[(size_t)q * 3 + 2];
  const float q2   = qx * qx + qy * qy + qz * qz;
  const float m2qx = -2.0f * qx, m2qy = -2.0f * qy, m2qz = -2.0f * qz;
  const float* pb = cpts + (size_t)b * C * 3;

  for (int i = threadIdx.x; i < C; i += 256) {
    const float x = pb[i * 3 + 0];
    const float y = pb[i * 3 + 1];
    const float z = pb[i * 3 + 2];
    sp[i] = make_float4(x, y, z, x * x + y * y + z * z);
  }
  __syncthreads();
  float best = INFINITY; int bi = 0x7fffffff;
  for (int base = 0; base < C; base += 64) {
    const float4 p = sp[base + lane];
    const float d = fmaf(m2qx, p.x, fmaf(m2qy, p.y, fmaf(m2qz, p.z, p.w + q2)));
    if (d < best) { best = d; bi = base + lane; }
  }
#pragma unroll
  for (int j = 1; j < 64; j <<= 1) {
    const float od = __shfl_xor(best, j);
    const int   oi = __shfl_xor(bi, j);
    if (od < best || (od == best && oi < bi)) { best = od; bi = oi; }
  }
  if (lane == 0) out[q] = bi;
}

// -------------------------------------------------------- conv_surface -----
__global__ void conv_surface_kernel(const float* __restrict__ verts,
                                    const int*   __restrict__ nb,
                                    const float* __restrict__ dir,
                                    int V, int C,
                                    ushort_t* __restrict__ outH,
                                    ushort_t* __restrict__ outL) {
  __shared__ float ux[32], uy[32], uz[32];
  const int bv = blockIdx.x;
  const int b = bv / V;
  const int v = bv - b * V;
  const float* vb = verts + (size_t)b * V * 3;
  if (threadIdx.x < 32) {
    const float cx = vb[v * 3 + 0], cy = vb[v * 3 + 1], cz = vb[v * 3 + 2];
    const int nidx = nb[(size_t)bv * 32 + threadIdx.x];
    const float dx = vb[nidx * 3 + 0] - cx;
    const float dy = vb[nidx * 3 + 1] - cy;
    const float dz = vb[nidx * 3 + 2] - cz;
    const float rn = 1.0f / fmaxf(sqrtf(dx * dx + dy * dy + dz * dz), 1e-12f);
    ux[threadIdx.x] = dx * rn; uy[threadIdx.x] = dy * rn; uz[threadIdx.x] = dz * rn;
  }
  __syncthreads();
  const int o = threadIdx.x;
  float d0 = dir[o], d1 = dir[C + o], d2 = dir[2 * C + o];
  const float rn = 1.0f / fmaxf(sqrtf(d0 * d0 + d1 * d1 + d2 * d2), 1e-12f);
  d0 *= rn; d1 *= rn; d2 *= rn;
  float m = -INFINITY;
#pragma unroll
  for (int n = 0; n < 32; ++n) {
    const float t = fmaxf(0.0f, fmaf(d2, uz[n], fmaf(d1, uy[n], d0 * ux[n])));
    m = fmaxf(m, t);
  }
  split_store(fmaxf(0.0f, m), outH, outL, (size_t)bv * C + o);
}

// -------------------------------------------------------- conv_combine -----
__global__ void conv_combine_kernel(const float* __restrict__ f,    // (B,V,2C)
                                    const int*   __restrict__ nb,
                                    const float* __restrict__ dir,
                                    const float* __restrict__ verts,
                                    int V, int C, int relu,
                                    ushort_t* __restrict__ outH,
                                    ushort_t* __restrict__ outL) {
  __shared__ float ux[32], uy[32], uz[32];
  __shared__ int snb[32];
  const int bv = blockIdx.x;
  const int b = bv / V;
  const int v = bv - b * V;
  const float* vb = verts + (size_t)b * V * 3;
  if (threadIdx.x < 32) {
    const float cx = vb[v * 3 + 0], cy = vb[v * 3 + 1], cz = vb[v * 3 + 2];
    const int nidx = nb[(size_t)bv * 32 + threadIdx.x];
    snb[threadIdx.x] = nidx;
    const float dx = vb[nidx * 3 + 0] - cx;
    const float dy = vb[nidx * 3 + 1] - cy;
    const float dz = vb[nidx * 3 + 2] - cz;
    const float rn = 1.0f / fmaxf(sqrtf(dx * dx + dy * dy + dz * dz), 1e-12f);
    ux[threadIdx.x] = dx * rn; uy[threadIdx.x] = dy * rn; uz[threadIdx.x] = dz * rn;
  }
  __syncthreads();
  const int o = threadIdx.x;
  float d0 = dir[o], d1 = dir[C + o], d2 = dir[2 * C + o];
  const float rn = 1.0f / fmaxf(sqrtf(d0 * d0 + d1 * d1 + d2 * d2), 1e-12f);
  d0 *= rn; d1 *= rn; d2 *= rn;
  const float* fb = f + (size_t)b * V * 2 * C;
  float m = -INFINITY;
#pragma unroll 8
  for (int n = 0; n < 32; ++n) {
    const float t = fmaxf(0.0f, fmaf(d2, uz[n], fmaf(d1, uy[n], d0 * ux[n])));
    const float s = fb[(size_t)snb[n] * 2 * C + C + o];
    m = fmaxf(m, t * s);
  }
  float r = fb[(size_t)v * 2 * C + o] + m;
  if (relu) r = fmaxf(r, 0.0f);
  split_store(r, outH, outL, (size_t)bv * C + o);
}

// ---------------------------------------------------------------- pool -----
__global__ void pool_kernel(const ushort_t* __restrict__ fmH,
                            const ushort_t* __restrict__ fmL,
                            const int*   __restrict__ nb,   // (B, Vsrc, 32)
                            const int*   __restrict__ sidx, // (Q,)
                            int Q, int Vsrc, int C,
                            ushort_t* __restrict__ outH,
                            ushort_t* __restrict__ outL) {
  const int i = blockIdx.x * blockDim.x + threadIdx.x;
  if (i >= B_ * Q * C) return;
  const int c = i % C;
  const int q = (i / C) % Q;
  const int b = i / (C * Q);
  const int* nn = nb + ((size_t)b * Vsrc + sidx[q]) * 32;
  const size_t fb = (size_t)b * Vsrc * C;
  float m = -INFINITY;
#pragma unroll
  for (int t = 0; t < 4; ++t) {
    const size_t idx = fb + (size_t)nn[t] * C + c;
    m = fmaxf(m, bf2f(fmH[idx]) + bf2f(fmL[idx]));
  }
  split_store(m, outH, outL, (size_t)i);
}

__global__ void gather_verts_kernel(const float* __restrict__ src,
                                    const int* __restrict__ idx,
                                    int Vsrc, int Q, float* __restrict__ dst) {
  const int i = blockIdx.x * blockDim.x + threadIdx.x;
  if (i >= B_ * Q * 3) return;
  const int c = i % 3;
  const int q = (i / 3) % Q;
  const int b = i / (3 * Q);
  dst[i] = src[((size_t)b * Vsrc + idx[q]) * 3 + c];
}

// grid = B_*8 blocks of 256 thr: 64 channels x 4 v-slices per block
__global__ void global_max_kernel(const ushort_t* __restrict__ fmH,
                                  const ushort_t* __restrict__ fmL,
                                  ushort_t* __restrict__ outH,
                                  ushort_t* __restrict__ outL) {
  __shared__ float red[4][64];
  const int t = threadIdx.x;
  const int cl = t & 63, slice = t >> 6;
  const int c = (blockIdx.x & 7) * 64 + cl;
  const int b = blockIdx.x >> 3;
  const size_t base = (size_t)b * 256 * 512 + c;
  float m = -INFINITY;
  for (int v = slice; v < 256; v += 4) {
    const size_t idx = base + (size_t)v * 512;
    m = fmaxf(m, bf2f(fmH[idx]) + bf2f(fmL[idx]));
  }
  red[slice][cl] = m;
  __syncthreads();
  if (slice == 0) {
    m = fmaxf(fmaxf(red[0][cl], red[1][cl]), fmaxf(red[2][cl], red[3][cl]));
    split_store(m, outH, outL, (size_t)b * 512 + c);
  }
}

// ------------------------------------------- split-bf16 MFMA GEMM ----------
// C = act(A @ B^T + bias); A (M,K), B (N,K) as hi/lo bf16 planes.
// acc += Al*Bh + Ah*Bl + Ah*Bh ~ fp32. 128x128 tile, BK=32, 4 waves 2x2.
// Staging via global_load_lds (16 B/lane DMA, no VGPR round-trip):
// LDS chunk-major [kchunk 4][row 128][8] per plane -> lane-linear writes,
// fragment reads at [quad][row] are 2-way bank-aliased = free (m136).
// Wave roles: wv0=A-hi, wv1=A-lo, wv2=B-hi, wv3=B-lo (8 loads each).
template<bool FUSE, bool SPLITOUT, bool RELU>
__launch_bounds__(256)
__global__ void mfma_gemm_kernel(
    const ushort_t* __restrict__ Ahi, const ushort_t* __restrict__ Alo,
    const ushort_t* __restrict__ f0h, const ushort_t* __restrict__ f0l,
    const ushort_t* __restrict__ f1h, const ushort_t* __restrict__ f1l,
    const ushort_t* __restrict__ f2h, const ushort_t* __restrict__ f2l,
    const ushort_t* __restrict__ f3h, const ushort_t* __restrict__ f3l,
    const ushort_t* __restrict__ f4h, const ushort_t* __restrict__ f4l,
    const ushort_t* __restrict__ fgh, const ushort_t* __restrict__ fgl,
    const int* __restrict__ near1, const int* __restrict__ near2,
    const ushort_t* __restrict__ Bhi, const ushort_t* __restrict__ Blo,
    const float* __restrict__ bias, int K,
    float* __restrict__ outF, ushort_t* __restrict__ outHi,
    ushort_t* __restrict__ outLo, int Nn)
{
  __shared__ ushort_t As_h[4 * 128 * 8];
  __shared__ ushort_t As_l[4 * 128 * 8];
  __shared__ ushort_t Bs_h[4 * 128 * 8];
  __shared__ ushort_t Bs_l[4 * 128 * 8];

  const int tid  = threadIdx.x;
  const int lane = tid & 63;
  const int wv   = tid >> 6;
  const int wr   = wv >> 1, wc = wv & 1;
  const int quad = lane >> 4, ml = lane & 15;
  const int m0 = blockIdx.y * 128, n0 = blockIdx.x * 128;

  // per-lane FUSE gather rows (rows lane and 64+lane), block-uniform batch
  int fb = 0, r1a = 0, r1b = 0, r2a = 0, r2b = 0;
  if (FUSE) {
    fb = m0 >> 12;                 // / 4096 (block-uniform: m0 % 128 == 0)
    r1a = near1[m0 + lane];      r1b = near1[m0 + 64 + lane];
    r2a = near2[m0 + lane];      r2b = near2[m0 + 64 + lane];
  }
  ushort_t* const tgt = (wv == 0) ? As_h : (wv == 1) ? As_l
                       : (wv == 2) ? Bs_h : Bs_l;
  const bool isA = (wv < 2);
  const bool isHi = ((wv & 1) == 0);

  f32x4 acc[4][4];
#pragma unroll
  for (int i = 0; i < 4; ++i)
#pragma unroll
    for (int j = 0; j < 4; ++j) acc[i][j] = f32x4{0.f, 0.f, 0.f, 0.f};

  for (int k0 = 0; k0 < K; k0 += 32) {
    __syncthreads();   // previous iteration's fragment reads complete
#pragma unroll
    for (int h = 0; h < 2; ++h) {
#pragma unroll
      for (int c = 0; c < 4; ++c) {
        const int k = k0 + c * 8;
        const ushort_t* src;
        if (!isA) {
          src = (isHi ? Bhi : Blo) + (size_t)(n0 + h * 64 + lane) * K + k;
        } else if (!FUSE) {
          src = (isHi ? Ahi : Alo) + (size_t)(m0 + h * 64 + lane) * K + k;
        } else {
          const int m = m0 + h * 64 + lane;
          const int rr1 = h ? r1b : r1a;
          const int rr2 = h ? r2b : r2a;
          const ushort_t* bp; size_t off;
          if (k < 128)       { bp = isHi ? f0h : f0l; off = (size_t)m * 128 + k; }
          else if (k < 256)  { bp = isHi ? f1h : f1l; off = (size_t)m * 128 + (k - 128); }
          else if (k < 512)  { bp = isHi ? f2h : f2l; off = ((size_t)fb * 1024 + rr1) * 256 + (k - 256); }
          else if (k < 768)  { bp = isHi ? f3h : f3l; off = ((size_t)fb * 1024 + rr1) * 256 + (k - 512); }
          else if (k < 1280) { bp = isHi ? f4h : f4l; off = ((size_t)fb * 256 + rr2) * 512 + (k - 768); }
          else               { bp = isHi ? fgh : fgl; off = (size_t)fb * 512 + (k - 1280); }
          src = bp + off;
        }
        async_copy16(src, &tgt[c * 1024 + h * 512]);
      }
    }
    __syncthreads();   // DMA drained (compiler emits vmcnt(0) before barrier)

    bf16x8 ah[4], al[4], bh[4], bl[4];
#pragma unroll
    for (int i = 0; i < 4; ++i) {
      const int row = wr * 64 + i * 16 + ml;
      ah[i] = *(const bf16x8*)&As_h[quad * 1024 + row * 8];
      al[i] = *(const bf16x8*)&As_l[quad * 1024 + row * 8];
    }
#pragma unroll
    for (int j = 0; j < 4; ++j) {
      const int row = wc * 64 + j * 16 + ml;
      bh[j] = *(const bf16x8*)&Bs_h[quad * 1024 + row * 8];
      bl[j] = *(const bf16x8*)&Bs_l[quad * 1024 + row * 8];
    }
#pragma unroll
    for (int i = 0; i < 4; ++i)
#pragma unroll
      for (int j = 0; j < 4; ++j) {
        acc[i][j] = __builtin_amdgcn_mfma_f32_16x16x32_bf16(al[i], bh[j], acc[i][j], 0, 0, 0);
        acc[i][j] = __builtin_amdgcn_mfma_f32_16x16x32_bf16(ah[i], bl[j], acc[i][j], 0, 0, 0);
        acc[i][j] = __builtin_amdgcn_mfma_f32_16x16x32_bf16(ah[i], bh[j], acc[i][j], 0, 0, 0);
      }
  }

  // epilogue: C/D mapping col=lane&15, row=quad*4+reg (m89)
#pragma unroll
  for (int i = 0; i < 4; ++i)
#pragma unroll
    for (int j = 0; j < 4; ++j) {
      const int n = n0 + wc * 64 + j * 16 + ml;
      const float bv = bias[n];
#pragma unroll
      for (int reg = 0; reg < 4; ++reg) {
        const int m = m0 + wr * 64 + i * 16 + quad * 4 + reg;
        float r = acc[i][j][reg] + bv;
        if (RELU) r = fmaxf(r, 0.0f);
        if (SPLITOUT) {
          const ushort_t h = f2bf_rne(r);
          outHi[(size_t)m * Nn + n] = h;
          outLo[(size_t)m * Nn + n] = f2bf_rne(r - bf2f(h));
        } else {
          outF[(size_t)m * Nn + n] = r;
        }
      }
    }
}

// ---------------------------------------------------------------- head -----
__global__ void head_kernel(const float* __restrict__ h,
                            const float* __restrict__ cw,
                            const float* __restrict__ cb,
                            float* __restrict__ out) {
  const int i = blockIdx.x * blockDim.x + threadIdx.x;
  if (i >= B_ * N0 * 13) return;
  const int o = i % 13;
  const int row = i / 13;
  const float4* hr = (const float4*)(h + (size_t)row * 512);
  const float4* wr = (const float4*)(cw + (size_t)o * 512);
  float acc = cb[o];
  for (int k = 0; k < 128; ++k) {
    const float4 a = hr[k], w = wr[k];
    acc = fmaf(a.x, w.x, fmaf(a.y, w.y, fmaf(a.z, w.z, fmaf(a.w, w.w, acc))));
  }
  out[i] = acc;
}

} // namespace

extern "C" void kernel_launch(void* const* d_in, const int* in_sizes, int n_in,
                              void* d_out, int out_size, void* d_ws, size_t ws_size,
                              hipStream_t stream)
{
  const float* vertices = (const float*)d_in[0];
  const int*   sidx1    = (const int*)  d_in[1];
  const int*   sidx2    = (const int*)  d_in[2];
  const float* dir0     = (const float*)d_in[3];
  const float* w1 = (const float*)d_in[4];
  const float* b1 = (const float*)d_in[5];
  const float* d1 = (const float*)d_in[6];
  const float* w2 = (const float*)d_in[7];
  const float* b2 = (const float*)d_in[8];
  const float* d2 = (const float*)d_in[9];
  const float* w3 = (const float*)d_in[10];
  const float* b3 = (const float*)d_in[11];
  const float* d3 = (const float*)d_in[12];
  const float* w4 = (const float*)d_in[13];
  const float* b4 = (const float*)d_in[14];
  const float* d4 = (const float*)d_in[15];
  const float* cw1 = (const float*)d_in[16];
  const float* cb1 = (const float*)d_in[17];
  const float* cw2 = (const float*)d_in[18];
  const float* cb2 = (const float*)d_in[19];
  const float* cw3 = (const float*)d_in[20];
  const float* cb3 = (const float*)d_in[21];
  (void)in_sizes; (void)n_in; (void)out_size; (void)ws_size;

  char* ws = (char*)d_ws;
  size_t off = 0;
  auto alloc = [&](size_t bytes) -> void* {
    void* p = ws + off;
    off += (bytes + 255) & ~(size_t)255;
    return p;
  };

  int*   nb1   = (int*)  alloc((size_t)B_ * N0 * 32 * 4);
  int*   nb2   = (int*)  alloc((size_t)B_ * N1 * 32 * 4);
  int*   nb3   = (int*)  alloc((size_t)B_ * N2 * 32 * 4);
  float* vp1   = (float*)alloc((size_t)B_ * N1 * 3 * 4);
  float* vp2   = (float*)alloc((size_t)B_ * N2 * 3 * 4);
  int*   near1 = (int*)  alloc((size_t)B_ * N0 * 4);
  int*   near2 = (int*)  alloc((size_t)B_ * N0 * 4);
  float* h2    = (float*)alloc((size_t)B_ * N0 * 512 * 4);   // 32 MB
  float* fbuf  = (float*)alloc((size_t)B_ * N0 * 256 * 4);   // 16 MB

  const size_t nF0 = (size_t)B_ * N0 * 128;   // fm0 / fm1
  const size_t nP1 = (size_t)B_ * N1 * 128;   // fmp1
  const size_t nF2 = (size_t)B_ * N1 * 256;   // fm2 / fm3
  const size_t nP2 = (size_t)B_ * N2 * 256;   // fmp2
  const size_t nF4 = (size_t)B_ * N2 * 512;
  const size_t nFg = (size_t)B_ * 512;
  const size_t nW1 = (size_t)512 * 1792;
  const size_t nW2 = (size_t)512 * 512;
  const size_t nH1 = (size_t)B_ * N0 * 512;
  ushort_t* f0h = (ushort_t*)alloc(nF0 * 2); ushort_t* f0l = (ushort_t*)alloc(nF0 * 2);
  ushort_t* f1h = (ushort_t*)alloc(nF0 * 2); ushort_t* f1l = (ushort_t*)alloc(nF0 * 2);
  ushort_t* p1h = (ushort_t*)alloc(nP1 * 2); ushort_t* p1l = (ushort_t*)alloc(nP1 * 2);
  ushort_t* f2h = (ushort_t*)alloc(nF2 * 2); ushort_t* f2l = (ushort_t*)alloc(nF2 * 2);
  ushort_t* f3h = (ushort_t*)alloc(nF2 * 2); ushort_t* f3l = (ushort_t*)alloc(nF2 * 2);
  ushort_t* p2h = (ushort_t*)alloc(nP2 * 2); ushort_t* p2l = (ushort_t*)alloc(nP2 * 2);
  ushort_t* f4h = (ushort_t*)alloc(nF4 * 2); ushort_t* f4l = (ushort_t*)alloc(nF4 * 2);
  ushort_t* fgh = (ushort_t*)alloc(nFg * 2); ushort_t* fgl = (ushort_t*)alloc(nFg * 2);
  ushort_t* w1h = (ushort_t*)alloc(nW1 * 2); ushort_t* w1l = (ushort_t*)alloc(nW1 * 2);
  ushort_t* w2h = (ushort_t*)alloc(nW2 * 2); ushort_t* w2l = (ushort_t*)alloc(nW2 * 2);
  ushort_t* h1h = (ushort_t*)alloc(nH1 * 2); ushort_t* h1l = (ushort_t*)alloc(nH1 * 2);
  ushort_t* w1th = (ushort_t*)alloc((size_t)256 * 128 * 2);
  ushort_t* w1tl = (ushort_t*)alloc((size_t)256 * 128 * 2);
  ushort_t* w2th = (ushort_t*)alloc((size_t)512 * 128 * 2);
  ushort_t* w2tl = (ushort_t*)alloc((size_t)512 * 128 * 2);
  ushort_t* w3th = (ushort_t*)alloc((size_t)512 * 256 * 2);
  ushort_t* w3tl = (ushort_t*)alloc((size_t)512 * 256 * 2);
  ushort_t* w4th = (ushort_t*)alloc((size_t)1024 * 256 * 2);
  ushort_t* w4tl = (ushort_t*)alloc((size_t)1024 * 256 * 2);

  const dim3 blk256(256), blk1024(1024);
  auto mgemm = [&](const ushort_t* Ah, const ushort_t* Al,
                   const ushort_t* Bh, const ushort_t* Bl, const float* bias,
                   int M, int Nn, int K, float* outF) {
    const dim3 grid(Nn / 128, M / 128);
    mfma_gemm_kernel<false, false, false><<<grid, blk256, 0, stream>>>(
        Ah, Al, nullptr, nullptr, nullptr, nullptr, nullptr, nullptr, nullptr,
        nullptr, nullptr, nullptr, nullptr, nullptr, nullptr, nullptr,
        Bh, Bl, bias, K, outF, nullptr, nullptr, Nn);
  };

  // ---- weight prep: single fused dispatch ----
  weight_prep_kernel<<<dim3(6528), blk256, 0, stream>>>(
      w1, w2, w3, w4, cw1, cw2,
      w1th, w1tl, w2th, w2tl, w3th, w3tl, w4th, w4tl,
      w1h, w1l, w2h, w2l);

  // ---- level 0 (4096 verts) ----
  knn_wave_kernel<32, 2048><<<dim3(N0 / 16, B_), blk1024, 0, stream>>>(vertices, N0, N0, nb1);
  conv_surface_kernel<<<dim3(B_ * N0), dim3(128), 0, stream>>>(
      vertices, nb1, dir0, N0, 128, f0h, f0l);
  mgemm(f0h, f0l, w1th, w1tl, b1, B_ * N0, 256, 128, fbuf);
  conv_combine_kernel<<<dim3(B_ * N0), dim3(128), 0, stream>>>(
      fbuf, nb1, d1, vertices, N0, 128, 1, f1h, f1l);

  // ---- pool 1 -> 1024 (top-4 = first 4 of nb1 rows at sidx1) ----
  gather_verts_kernel<<<dim3((B_ * N1 * 3 + 255) / 256), blk256, 0, stream>>>(vertices, sidx1, N0, N1, vp1);
  pool_kernel<<<dim3((B_ * N1 * 128 + 255) / 256), blk256, 0, stream>>>(
      f1h, f1l, nb1, sidx1, N1, N0, 128, p1h, p1l);

  // ---- level 1 (1024 verts) ----
  knn_wave_kernel<32, 1024><<<dim3(N1 / 16, B_), blk1024, 0, stream>>>(vp1, N1, N1, nb2);
  mgemm(p1h, p1l, w2th, w2tl, b2, B_ * N1, 512, 128, fbuf);
  conv_combine_kernel<<<dim3(B_ * N1), dim3(256), 0, stream>>>(
      fbuf, nb2, d2, vp1, N1, 256, 1, f2h, f2l);
  mgemm(f2h, f2l, w3th, w3tl, b3, B_ * N1, 512, 256, fbuf);
  conv_combine_kernel<<<dim3(B_ * N1), dim3(256), 0, stream>>>(
      fbuf, nb2, d3, vp1, N1, 256, 1, f3h, f3l);

  // ---- pool 2 -> 256 ----
  gather_verts_kernel<<<dim3((B_ * N2 * 3 + 255) / 256), blk256, 0, stream>>>(vp1, sidx2, N1, N2, vp2);
  pool_kernel<<<dim3((B_ * N2 * 256 + 255) / 256), blk256, 0, stream>>>(
      f3h, f3l, nb2, sidx2, N2, N1, 256, p2h, p2l);

  // ---- level 2 (256 verts) ----
  knn_wave_kernel<32, 256><<<dim3(N2 / 16, B_), blk1024, 0, stream>>>(vp2, N2, N2, nb3);
  mgemm(p2h, p2l, w4th, w4tl, b4, B_ * N2, 1024, 256, fbuf);
  conv_combine_kernel<<<dim3(B_ * N2), dim3(512), 0, stream>>>(
      fbuf, nb3, d4, vp2, N2, 512, 0, f4h, f4l);     // no relu on fm_4
  global_max_kernel<<<dim3(B_ * 8), blk256, 0, stream>>>(f4h, f4l, fgh, fgl);

  // ---- upsample indices: both levels in one dispatch ----
  nearest_dual_kernel<<<dim3((B_ * N0) / 4, 2), blk256, 0, stream>>>(
      vertices, vp1, vp2, near1, near2);

  // ---- head MLP ----
  mfma_gemm_kernel<true, true, true><<<dim3(512 / 128, (B_ * N0) / 128), blk256, 0, stream>>>(
      nullptr, nullptr,
      f0h, f0l, f1h, f1l, f2h, f2l, f3h, f3l, f4h, f4l, fgh, fgl,
      near1, near2, w1h, w1l, cb1, 1792, nullptr, h1h, h1l, 512);
  mfma_gemm_kernel<false, false, true><<<dim3(512 / 128, (B_ * N0) / 128), blk256, 0, stream>>>(
      h1h, h1l,
      nullptr, nullptr, nullptr, nullptr, nullptr, nullptr, nullptr, nullptr,
      nullptr, nullptr, nullptr, nullptr,
      nullptr, nullptr, w2h, w2l, cb2, 512, h2, nullptr, nullptr, 512);
  head_kernel<<<dim3((B_ * N0 * 13 + 255) / 256), blk256, 0, stream>>>(h2, cw3, cb3, (float*)d_out);
}

// Round 10
// 666.526 us; speedup vs baseline: 1.1343x; 1.1343x over previous
//
#include <hip/hip_runtime.h>
#include <cstdint>
#include <cstddef>

namespace {

typedef unsigned short ushort_t;
typedef __bf16 bf16x8 __attribute__((ext_vector_type(8)));
typedef float  f32x4  __attribute__((ext_vector_type(4)));

constexpr int B_ = 4;
constexpr int N0 = 4096;   // vertices per batch
constexpr int N1 = 1024;   // after pool1
constexpr int N2 = 256;    // after pool2

// ----------------------------------------------------- bf16 split utils ----
__device__ __forceinline__ ushort_t f2bf_rne(float x) {
  uint32_t b = __float_as_uint(x);
  b += 0x7FFFu + ((b >> 16) & 1u);
  return (ushort_t)(b >> 16);
}
__device__ __forceinline__ float bf2f(ushort_t h) {
  return __uint_as_float(((uint32_t)h) << 16);
}
__device__ __forceinline__ void split_store(float x, ushort_t* hi, ushort_t* lo,
                                            size_t i) {
  const ushort_t h = f2bf_rne(x);
  hi[i] = h;
  lo[i] = f2bf_rne(x - bf2f(h));
}

// --------------------------------------- fused weight prep (one dispatch) --
__global__ void weight_prep_kernel(
    const float* __restrict__ w1, const float* __restrict__ w2,
    const float* __restrict__ w3, const float* __restrict__ w4,
    const float* __restrict__ cw1, const float* __restrict__ cw2,
    ushort_t* __restrict__ w1th, ushort_t* __restrict__ w1tl,
    ushort_t* __restrict__ w2th, ushort_t* __restrict__ w2tl,
    ushort_t* __restrict__ w3th, ushort_t* __restrict__ w3tl,
    ushort_t* __restrict__ w4th, ushort_t* __restrict__ w4tl,
    ushort_t* __restrict__ w1h, ushort_t* __restrict__ w1l,
    ushort_t* __restrict__ w2h, ushort_t* __restrict__ w2l)
{
  const int i = blockIdx.x * blockDim.x + threadIdx.x;
  if (i < 32768) {                       // w1: K=128, N=256
    const int j = i, k = j % 128, n = j / 128;
    split_store(w1[(size_t)k * 256 + n], w1th, w1tl, (size_t)n * 128 + k);
  } else if (i < 98304) {                // w2: K=128, N=512
    const int j = i - 32768, k = j % 128, n = j / 128;
    split_store(w2[(size_t)k * 512 + n], w2th, w2tl, (size_t)n * 128 + k);
  } else if (i < 229376) {               // w3: K=256, N=512
    const int j = i - 98304, k = j % 256, n = j / 256;
    split_store(w3[(size_t)k * 512 + n], w3th, w3tl, (size_t)n * 256 + k);
  } else if (i < 491520) {               // w4: K=256, N=1024
    const int j = i - 229376, k = j % 256, n = j / 256;
    split_store(w4[(size_t)k * 1024 + n], w4th, w4tl, (size_t)n * 256 + k);
  } else if (i < 1409024) {              // cw1: already (N,K)
    const int j = i - 491520;
    split_store(cw1[j], w1h, w1l, j);
  } else if (i < 1671168) {              // cw2
    const int j = i - 1409024;
    split_store(cw2[j], w2h, w2l, j);
  }
}

// ------------------------------------------------- wave-cooperative KNN ----
__device__ __forceinline__ void bitonic_sort64(float& sd, int& si, int lane) {
#pragma unroll
  for (int kk = 2; kk <= 64; kk <<= 1) {
#pragma unroll
    for (int j = kk >> 1; j > 0; j >>= 1) {
      const float od = __shfl_xor(sd, j);
      const int   oi = __shfl_xor(si, j);
      const bool less    = (sd < od) || (sd == od && si < oi);
      const bool wantMin = ((lane & j) == 0) == ((lane & kk) == 0);
      if (wantMin != less) { sd = od; si = oi; }
    }
  }
}

__device__ __forceinline__ void knn_flush(float& ld, int& li, float& tau,
                                          int cnt, const float* bufd,
                                          const int* bufi, int lane, int Km1) {
  float sd = (lane < cnt) ? bufd[lane] : INFINITY;
  int   si = (lane < cnt) ? bufi[lane] : 0x7fffffff;
  bitonic_sort64(sd, si, lane);
  const float rd = __shfl(sd, 63 - lane);
  const int   ri = __shfl(si, 63 - lane);
  const bool keep = (ld < rd) || (ld == rd && li < ri);
  float md = keep ? ld : rd;
  int   mi = keep ? li : ri;
#pragma unroll
  for (int j = 32; j > 0; j >>= 1) {
    const float od = __shfl_xor(md, j);
    const int   oi = __shfl_xor(mi, j);
    const bool less    = (md < od) || (md == od && mi < oi);
    const bool wantMin = ((lane & j) == 0);
    if (wantMin != less) { md = od; mi = oi; }
  }
  ld = md; li = mi;
  tau = __shfl(ld, Km1);
}

// 16 waves/block (one query each); LDS tiles of (x,y,z,|p|^2) shared by all.
template<int K, int TILE>
__launch_bounds__(1024)
__global__ void knn_wave_kernel(const float* __restrict__ pts,   // (B, C, 3)
                                int Q, int C,
                                int* __restrict__ out)           // (B, Q, K)
{
  __shared__ float4 sp[TILE];
  __shared__ float sbd[16][64];
  __shared__ int   sbi[16][64];
  const int b    = blockIdx.y;
  const int lane = threadIdx.x & 63;
  const int wid  = threadIdx.x >> 6;
  const int q    = blockIdx.x * 16 + wid;
  const int self = q;
  const float* pb = pts + (size_t)b * C * 3;
  const float qx = pb[self * 3 + 0];
  const float qy = pb[self * 3 + 1];
  const float qz = pb[self * 3 + 2];
  const float q2   = qx * qx + qy * qy + qz * qz;
  const float m2qx = -2.0f * qx, m2qy = -2.0f * qy, m2qz = -2.0f * qz;

  float ld = INFINITY; int li = 0x7fffffff;
  float tau = INFINITY;
  int cnt = 0;
  float* bufd = sbd[wid];
  int*   bufi = sbi[wid];

  auto append = [&](unsigned long long m, bool cand, float d, int ci) {
    const int c = __popcll(m);
    if (cnt + c > 64) {
      knn_flush(ld, li, tau, cnt, bufd, bufi, lane, K - 1);
      cnt = 0;
    }
    const int prefix = __popcll(m & ((1ull << lane) - 1ull));
    if (cand) { bufd[cnt + prefix] = d; bufi[cnt + prefix] = ci; }
    cnt += c;
  };

  for (int t0 = 0; t0 < C; t0 += TILE) {
    __syncthreads();
    for (int i = threadIdx.x; i < TILE; i += 1024) {
      const float x = pb[(t0 + i) * 3 + 0];
      const float y = pb[(t0 + i) * 3 + 1];
      const float z = pb[(t0 + i) * 3 + 2];
      sp[i] = make_float4(x, y, z, x * x + y * y + z * z);
    }
    __syncthreads();
    int base = 0;
    if (t0 == 0) {
      const float4 p = sp[lane];
      const float d = fmaf(m2qx, p.x, fmaf(m2qy, p.y, fmaf(m2qz, p.z, p.w + q2)));
      const bool valid = (lane != self);
      float sd = valid ? d : INFINITY;
      int   si = valid ? lane : 0x7fffffff;
      bitonic_sort64(sd, si, lane);
      ld = sd; li = si;
      tau = __shfl(ld, K - 1);
      base = 64;
    }
    for (; base + 128 <= TILE; base += 128) {
      const int ci0 = t0 + base + lane;
      const int ci1 = ci0 + 64;
      const float4 p0 = sp[base + lane];
      const float4 p1 = sp[base + 64 + lane];
      const float d0 = fmaf(m2qx, p0.x, fmaf(m2qy, p0.y, fmaf(m2qz, p0.z, p0.w + q2)));
      const float d1 = fmaf(m2qx, p1.x, fmaf(m2qy, p1.y, fmaf(m2qz, p1.z, p1.w + q2)));
      const bool c0 = (ci0 != self) && (d0 < tau);
      const bool c1 = (ci1 != self) && (d1 < tau);
      const unsigned long long m0 = __ballot(c0);
      const unsigned long long m1 = __ballot(c1);
      if (m0) append(m0, c0, d0, ci0);
      if (m1) append(m1, c1, d1, ci1);
    }
    if (base < TILE) {                   // 64-tail (first tile only)
      const int ci = t0 + base + lane;
      const float4 p = sp[base + lane];
      const float d = fmaf(m2qx, p.x, fmaf(m2qy, p.y, fmaf(m2qz, p.z, p.w + q2)));
      const bool c = (ci != self) && (d < tau);
      const unsigned long long m = __ballot(c);
      if (m) append(m, c, d, ci);
    }
  }
  if (cnt > 0) knn_flush(ld, li, tau, cnt, bufd, bufi, lane, K - 1);
  if (lane < K) out[((size_t)b * Q + q) * K + lane] = li;
}

// -------------------------------------------- dual-level wave argmin -------
__launch_bounds__(256)
__global__ void nearest_dual_kernel(const float* __restrict__ qpts, // (B*N0,3)
                                    const float* __restrict__ cpts1,
                                    const float* __restrict__ cpts2,
                                    int* __restrict__ out1,
                                    int* __restrict__ out2)
{
  __shared__ float4 sp[1024];
  const int lvl = blockIdx.y;
  const int C = lvl ? N2 : N1;
  const float* cpts = lvl ? cpts2 : cpts1;
  int* out = lvl ? out2 : out1;
  const int lane = threadIdx.x & 63;
  const int wid  = threadIdx.x >> 6;
  const int q    = blockIdx.x * 4 + wid;        // over B_*N0
  const int b    = q >> 12;                     // / 4096
  const float qx = qpts[(size_t)q * 3 + 0];
  const float qy = qpts[(size_t)q * 3 + 1];
  const float qz = qpts[(size_t)q * 3 + 2];
  const float q2   = qx * qx + qy * qy + qz * qz;
  const float m2qx = -2.0f * qx, m2qy = -2.0f * qy, m2qz = -2.0f * qz;
  const float* pb = cpts + (size_t)b * C * 3;

  for (int i = threadIdx.x; i < C; i += 256) {
    const float x = pb[i * 3 + 0];
    const float y = pb[i * 3 + 1];
    const float z = pb[i * 3 + 2];
    sp[i] = make_float4(x, y, z, x * x + y * y + z * z);
  }
  __syncthreads();
  float best = INFINITY; int bi = 0x7fffffff;
  for (int base = 0; base < C; base += 64) {
    const float4 p = sp[base + lane];
    const float d = fmaf(m2qx, p.x, fmaf(m2qy, p.y, fmaf(m2qz, p.z, p.w + q2)));
    if (d < best) { best = d; bi = base + lane; }
  }
#pragma unroll
  for (int j = 1; j < 64; j <<= 1) {
    const float od = __shfl_xor(best, j);
    const int   oi = __shfl_xor(bi, j);
    if (od < best || (od == best && oi < bi)) { best = od; bi = oi; }
  }
  if (lane == 0) out[q] = bi;
}

// -------------------------------------------------------- conv_surface -----
__global__ void conv_surface_kernel(const float* __restrict__ verts,
                                    const int*   __restrict__ nb,
                                    const float* __restrict__ dir,
                                    int V, int C,
                                    ushort_t* __restrict__ outH,
                                    ushort_t* __restrict__ outL) {
  __shared__ float ux[32], uy[32], uz[32];
  const int bv = blockIdx.x;
  const int b = bv / V;
  const int v = bv - b * V;
  const float* vb = verts + (size_t)b * V * 3;
  if (threadIdx.x < 32) {
    const float cx = vb[v * 3 + 0], cy = vb[v * 3 + 1], cz = vb[v * 3 + 2];
    const int nidx = nb[(size_t)bv * 32 + threadIdx.x];
    const float dx = vb[nidx * 3 + 0] - cx;
    const float dy = vb[nidx * 3 + 1] - cy;
    const float dz = vb[nidx * 3 + 2] - cz;
    const float rn = 1.0f / fmaxf(sqrtf(dx * dx + dy * dy + dz * dz), 1e-12f);
    ux[threadIdx.x] = dx * rn; uy[threadIdx.x] = dy * rn; uz[threadIdx.x] = dz * rn;
  }
  __syncthreads();
  const int o = threadIdx.x;
  float d0 = dir[o], d1 = dir[C + o], d2 = dir[2 * C + o];
  const float rn = 1.0f / fmaxf(sqrtf(d0 * d0 + d1 * d1 + d2 * d2), 1e-12f);
  d0 *= rn; d1 *= rn; d2 *= rn;
  float m = -INFINITY;
#pragma unroll
  for (int n = 0; n < 32; ++n) {
    const float t = fmaxf(0.0f, fmaf(d2, uz[n], fmaf(d1, uy[n], d0 * ux[n])));
    m = fmaxf(m, t);
  }
  split_store(fmaxf(0.0f, m), outH, outL, (size_t)bv * C + o);
}

// -------------------------------------------------------- conv_combine -----
__global__ void conv_combine_kernel(const float* __restrict__ f,    // (B,V,2C)
                                    const int*   __restrict__ nb,
                                    const float* __restrict__ dir,
                                    const float* __restrict__ verts,
                                    int V, int C, int relu,
                                    ushort_t* __restrict__ outH,
                                    ushort_t* __restrict__ outL) {
  __shared__ float ux[32], uy[32], uz[32];
  __shared__ int snb[32];
  const int bv = blockIdx.x;
  const int b = bv / V;
  const int v = bv - b * V;
  const float* vb = verts + (size_t)b * V * 3;
  if (threadIdx.x < 32) {
    const float cx = vb[v * 3 + 0], cy = vb[v * 3 + 1], cz = vb[v * 3 + 2];
    const int nidx = nb[(size_t)bv * 32 + threadIdx.x];
    snb[threadIdx.x] = nidx;
    const float dx = vb[nidx * 3 + 0] - cx;
    const float dy = vb[nidx * 3 + 1] - cy;
    const float dz = vb[nidx * 3 + 2] - cz;
    const float rn = 1.0f / fmaxf(sqrtf(dx * dx + dy * dy + dz * dz), 1e-12f);
    ux[threadIdx.x] = dx * rn; uy[threadIdx.x] = dy * rn; uz[threadIdx.x] = dz * rn;
  }
  __syncthreads();
  const int o = threadIdx.x;
  float d0 = dir[o], d1 = dir[C + o], d2 = dir[2 * C + o];
  const float rn = 1.0f / fmaxf(sqrtf(d0 * d0 + d1 * d1 + d2 * d2), 1e-12f);
  d0 *= rn; d1 *= rn; d2 *= rn;
  const float* fb = f + (size_t)b * V * 2 * C;
  float m = -INFINITY;
#pragma unroll 8
  for (int n = 0; n < 32; ++n) {
    const float t = fmaxf(0.0f, fmaf(d2, uz[n], fmaf(d1, uy[n], d0 * ux[n])));
    const float s = fb[(size_t)snb[n] * 2 * C + C + o];
    m = fmaxf(m, t * s);
  }
  float r = fb[(size_t)v * 2 * C + o] + m;
  if (relu) r = fmaxf(r, 0.0f);
  split_store(r, outH, outL, (size_t)bv * C + o);
}

// ---------------------------------------------------------------- pool -----
__global__ void pool_kernel(const ushort_t* __restrict__ fmH,
                            const ushort_t* __restrict__ fmL,
                            const int*   __restrict__ nb,   // (B, Vsrc, 32)
                            const int*   __restrict__ sidx, // (Q,)
                            int Q, int Vsrc, int C,
                            ushort_t* __restrict__ outH,
                            ushort_t* __restrict__ outL) {
  const int i = blockIdx.x * blockDim.x + threadIdx.x;
  if (i >= B_ * Q * C) return;
  const int c = i % C;
  const int q = (i / C) % Q;
  const int b = i / (C * Q);
  const int* nn = nb + ((size_t)b * Vsrc + sidx[q]) * 32;
  const size_t fb = (size_t)b * Vsrc * C;
  float m = -INFINITY;
#pragma unroll
  for (int t = 0; t < 4; ++t) {
    const size_t idx = fb + (size_t)nn[t] * C + c;
    m = fmaxf(m, bf2f(fmH[idx]) + bf2f(fmL[idx]));
  }
  split_store(m, outH, outL, (size_t)i);
}

__global__ void gather_verts_kernel(const float* __restrict__ src,
                                    const int* __restrict__ idx,
                                    int Vsrc, int Q, float* __restrict__ dst) {
  const int i = blockIdx.x * blockDim.x + threadIdx.x;
  if (i >= B_ * Q * 3) return;
  const int c = i % 3;
  const int q = (i / 3) % Q;
  const int b = i / (3 * Q);
  dst[i] = src[((size_t)b * Vsrc + idx[q]) * 3 + c];
}

// grid = B_*8 blocks of 256 thr: 64 channels x 4 v-slices per block
__global__ void global_max_kernel(const ushort_t* __restrict__ fmH,
                                  const ushort_t* __restrict__ fmL,
                                  ushort_t* __restrict__ outH,
                                  ushort_t* __restrict__ outL) {
  __shared__ float red[4][64];
  const int t = threadIdx.x;
  const int cl = t & 63, slice = t >> 6;
  const int c = (blockIdx.x & 7) * 64 + cl;
  const int b = blockIdx.x >> 3;
  const size_t base = (size_t)b * 256 * 512 + c;
  float m = -INFINITY;
  for (int v = slice; v < 256; v += 4) {
    const size_t idx = base + (size_t)v * 512;
    m = fmaxf(m, bf2f(fmH[idx]) + bf2f(fmL[idx]));
  }
  red[slice][cl] = m;
  __syncthreads();
  if (slice == 0) {
    m = fmaxf(fmaxf(red[0][cl], red[1][cl]), fmaxf(red[2][cl], red[3][cl]));
    split_store(m, outH, outL, (size_t)b * 512 + c);
  }
}

// ------------------------------------------- split-bf16 MFMA GEMM ----------
// C = act(A @ B^T + bias); A (M,K), B (N,K) as hi/lo bf16 planes.
// acc += Al*Bh + Ah*Bl + Ah*Bh (3 MFMA shared fp32 accumulator) ~ fp32.
// 128x128 tile, BK=32, 4 waves 2x2, each wave 4x4 16x16x32 frags.
// Round-8 staging (VGPR+ds_write, thread-pair 32B-contiguous loads) — the
// global_load_lds variant (round 9) regressed at this 2-block/CU occupancy:
// the vmcnt(0) barrier drain is unhidden and lane-per-row DMA uncoalesces.
constexpr int LDT = 40;  // LDS row stride in ushorts (32 + 8 pad)

template<bool FUSE, bool SPLITOUT, bool RELU>
__launch_bounds__(256)
__global__ void mfma_gemm_kernel(
    const ushort_t* __restrict__ Ahi, const ushort_t* __restrict__ Alo,
    const ushort_t* __restrict__ f0h, const ushort_t* __restrict__ f0l,
    const ushort_t* __restrict__ f1h, const ushort_t* __restrict__ f1l,
    const ushort_t* __restrict__ f2h, const ushort_t* __restrict__ f2l,
    const ushort_t* __restrict__ f3h, const ushort_t* __restrict__ f3l,
    const ushort_t* __restrict__ f4h, const ushort_t* __restrict__ f4l,
    const ushort_t* __restrict__ fgh, const ushort_t* __restrict__ fgl,
    const int* __restrict__ near1, const int* __restrict__ near2,
    const ushort_t* __restrict__ Bhi, const ushort_t* __restrict__ Blo,
    const float* __restrict__ bias, int K,
    float* __restrict__ outF, ushort_t* __restrict__ outHi,
    ushort_t* __restrict__ outLo, int Nn)
{
  __shared__ ushort_t As_h[128 * LDT];
  __shared__ ushort_t As_l[128 * LDT];
  __shared__ ushort_t Bs_h[128 * LDT];
  __shared__ ushort_t Bs_l[128 * LDT];

  const int tid  = threadIdx.x;
  const int lane = tid & 63;
  const int wv   = tid >> 6;
  const int wr   = wv >> 1, wc = wv & 1;
  const int quad = lane >> 4, ml = lane & 15;
  const int m0 = blockIdx.y * 128, n0 = blockIdx.x * 128;

  const int r  = tid >> 1;         // staging row 0..127
  const int hh = (tid & 1) * 16;   // 16-elem half of BK=32

  int fb = 0, r1 = 0, r2 = 0;
  if (FUSE) {
    const int m = m0 + r;
    fb = m >> 12;                  // / 4096
    r1 = near1[m];
    r2 = near2[m];
  }

  f32x4 acc[4][4];
#pragma unroll
  for (int i = 0; i < 4; ++i)
#pragma unroll
    for (int j = 0; j < 4; ++j) acc[i][j] = f32x4{0.f, 0.f, 0.f, 0.f};

  for (int k0 = 0; k0 < K; k0 += 32) {
    const int k = k0 + hh;
    uint4 a0h, a1h, a0l, a1l;
    {
      const ushort_t *sh, *sl; size_t off;
      if (FUSE) {
        const int m = m0 + r;
        if (k < 128)       { sh = f0h; sl = f0l; off = (size_t)m * 128 + k; }
        else if (k < 256)  { sh = f1h; sl = f1l; off = (size_t)m * 128 + (k - 128); }
        else if (k < 512)  { sh = f2h; sl = f2l; off = ((size_t)fb * 1024 + r1) * 256 + (k - 256); }
        else if (k < 768)  { sh = f3h; sl = f3l; off = ((size_t)fb * 1024 + r1) * 256 + (k - 512); }
        else if (k < 1280) { sh = f4h; sl = f4l; off = ((size_t)fb * 256 + r2) * 512 + (k - 768); }
        else               { sh = fgh; sl = fgl; off = (size_t)fb * 512 + (k - 1280); }
      } else {
        sh = Ahi; sl = Alo; off = (size_t)(m0 + r) * K + k;
      }
      a0h = *(const uint4*)(sh + off); a1h = *(const uint4*)(sh + off + 8);
      a0l = *(const uint4*)(sl + off); a1l = *(const uint4*)(sl + off + 8);
    }
    uint4 b0h, b1h, b0l, b1l;
    {
      const size_t off = (size_t)(n0 + r) * K + k;
      b0h = *(const uint4*)(Bhi + off); b1h = *(const uint4*)(Bhi + off + 8);
      b0l = *(const uint4*)(Blo + off); b1l = *(const uint4*)(Blo + off + 8);
    }
    __syncthreads();   // previous iteration's fragment reads complete
    *(uint4*)&As_h[r * LDT + hh]     = a0h;
    *(uint4*)&As_h[r * LDT + hh + 8] = a1h;
    *(uint4*)&As_l[r * LDT + hh]     = a0l;
    *(uint4*)&As_l[r * LDT + hh + 8] = a1l;
    *(uint4*)&Bs_h[r * LDT + hh]     = b0h;
    *(uint4*)&Bs_h[r * LDT + hh + 8] = b1h;
    *(uint4*)&Bs_l[r * LDT + hh]     = b0l;
    *(uint4*)&Bs_l[r * LDT + hh + 8] = b1l;
    __syncthreads();

    bf16x8 ah[4], al[4], bh[4], bl[4];
#pragma unroll
    for (int i = 0; i < 4; ++i) {
      const int row = wr * 64 + i * 16 + ml;
      ah[i] = *(const bf16x8*)&As_h[row * LDT + quad * 8];
      al[i] = *(const bf16x8*)&As_l[row * LDT + quad * 8];
    }
#pragma unroll
    for (int j = 0; j < 4; ++j) {
      const int row = wc * 64 + j * 16 + ml;
      bh[j] = *(const bf16x8*)&Bs_h[row * LDT + quad * 8];
      bl[j] = *(const bf16x8*)&Bs_l[row * LDT + quad * 8];
    }
#pragma unroll
    for (int i = 0; i < 4; ++i)
#pragma unroll
      for (int j = 0; j < 4; ++j) {
        acc[i][j] = __builtin_amdgcn_mfma_f32_16x16x32_bf16(al[i], bh[j], acc[i][j], 0, 0, 0);
        acc[i][j] = __builtin_amdgcn_mfma_f32_16x16x32_bf16(ah[i], bl[j], acc[i][j], 0, 0, 0);
        acc[i][j] = __builtin_amdgcn_mfma_f32_16x16x32_bf16(ah[i], bh[j], acc[i][j], 0, 0, 0);
      }
  }

  // epilogue: C/D mapping col=lane&15, row=quad*4+reg (m89)
#pragma unroll
  for (int i = 0; i < 4; ++i)
#pragma unroll
    for (int j = 0; j < 4; ++j) {
      const int n = n0 + wc * 64 + j * 16 + ml;
      const float bv = bias[n];
#pragma unroll
      for (int reg = 0; reg < 4; ++reg) {
        const int m = m0 + wr * 64 + i * 16 + quad * 4 + reg;
        float r = acc[i][j][reg] + bv;
        if (RELU) r = fmaxf(r, 0.0f);
        if (SPLITOUT) {
          const ushort_t h = f2bf_rne(r);
          outHi[(size_t)m * Nn + n] = h;
          outLo[(size_t)m * Nn + n] = f2bf_rne(r - bf2f(h));
        } else {
          outF[(size_t)m * Nn + n] = r;
        }
      }
    }
}

// ---------------------------------------------------------------- head -----
__global__ void head_kernel(const float* __restrict__ h,
                            const float* __restrict__ cw,
                            const float* __restrict__ cb,
                            float* __restrict__ out) {
  const int i = blockIdx.x * blockDim.x + threadIdx.x;
  if (i >= B_ * N0 * 13) return;
  const int o = i % 13;
  const int row = i / 13;
  const float4* hr = (const float4*)(h + (size_t)row * 512);
  const float4* wr = (const float4*)(cw + (size_t)o * 512);
  float acc = cb[o];
  for (int k = 0; k < 128; ++k) {
    const float4 a = hr[k], w = wr[k];
    acc = fmaf(a.x, w.x, fmaf(a.y, w.y, fmaf(a.z, w.z, fmaf(a.w, w.w, acc))));
  }
  out[i] = acc;
}

} // namespace

extern "C" void kernel_launch(void* const* d_in, const int* in_sizes, int n_in,
                              void* d_out, int out_size, void* d_ws, size_t ws_size,
                              hipStream_t stream)
{
  const float* vertices = (const float*)d_in[0];
  const int*   sidx1    = (const int*)  d_in[1];
  const int*   sidx2    = (const int*)  d_in[2];
  const float* dir0     = (const float*)d_in[3];
  const float* w1 = (const float*)d_in[4];
  const float* b1 = (const float*)d_in[5];
  const float* d1 = (const float*)d_in[6];
  const float* w2 = (const float*)d_in[7];
  const float* b2 = (const float*)d_in[8];
  const float* d2 = (const float*)d_in[9];
  const float* w3 = (const float*)d_in[10];
  const float* b3 = (const float*)d_in[11];
  const float* d3 = (const float*)d_in[12];
  const float* w4 = (const float*)d_in[13];
  const float* b4 = (const float*)d_in[14];
  const float* d4 = (const float*)d_in[15];
  const float* cw1 = (const float*)d_in[16];
  const float* cb1 = (const float*)d_in[17];
  const float* cw2 = (const float*)d_in[18];
  const float* cb2 = (const float*)d_in[19];
  const float* cw3 = (const float*)d_in[20];
  const float* cb3 = (const float*)d_in[21];
  (void)in_sizes; (void)n_in; (void)out_size; (void)ws_size;

  char* ws = (char*)d_ws;
  size_t off = 0;
  auto alloc = [&](size_t bytes) -> void* {
    void* p = ws + off;
    off += (bytes + 255) & ~(size_t)255;
    return p;
  };

  int*   nb1   = (int*)  alloc((size_t)B_ * N0 * 32 * 4);
  int*   nb2   = (int*)  alloc((size_t)B_ * N1 * 32 * 4);
  int*   nb3   = (int*)  alloc((size_t)B_ * N2 * 32 * 4);
  float* vp1   = (float*)alloc((size_t)B_ * N1 * 3 * 4);
  float* vp2   = (float*)alloc((size_t)B_ * N2 * 3 * 4);
  int*   near1 = (int*)  alloc((size_t)B_ * N0 * 4);
  int*   near2 = (int*)  alloc((size_t)B_ * N0 * 4);
  float* h2    = (float*)alloc((size_t)B_ * N0 * 512 * 4);   // 32 MB
  float* fbuf  = (float*)alloc((size_t)B_ * N0 * 256 * 4);   // 16 MB

  const size_t nF0 = (size_t)B_ * N0 * 128;   // fm0 / fm1
  const size_t nP1 = (size_t)B_ * N1 * 128;   // fmp1
  const size_t nF2 = (size_t)B_ * N1 * 256;   // fm2 / fm3
  const size_t nP2 = (size_t)B_ * N2 * 256;   // fmp2
  const size_t nF4 = (size_t)B_ * N2 * 512;
  const size_t nFg = (size_t)B_ * 512;
  const size_t nW1 = (size_t)512 * 1792;
  const size_t nW2 = (size_t)512 * 512;
  const size_t nH1 = (size_t)B_ * N0 * 512;
  ushort_t* f0h = (ushort_t*)alloc(nF0 * 2); ushort_t* f0l = (ushort_t*)alloc(nF0 * 2);
  ushort_t* f1h = (ushort_t*)alloc(nF0 * 2); ushort_t* f1l = (ushort_t*)alloc(nF0 * 2);
  ushort_t* p1h = (ushort_t*)alloc(nP1 * 2); ushort_t* p1l = (ushort_t*)alloc(nP1 * 2);
  ushort_t* f2h = (ushort_t*)alloc(nF2 * 2); ushort_t* f2l = (ushort_t*)alloc(nF2 * 2);
  ushort_t* f3h = (ushort_t*)alloc(nF2 * 2); ushort_t* f3l = (ushort_t*)alloc(nF2 * 2);
  ushort_t* p2h = (ushort_t*)alloc(nP2 * 2); ushort_t* p2l = (ushort_t*)alloc(nP2 * 2);
  ushort_t* f4h = (ushort_t*)alloc(nF4 * 2); ushort_t* f4l = (ushort_t*)alloc(nF4 * 2);
  ushort_t* fgh = (ushort_t*)alloc(nFg * 2); ushort_t* fgl = (ushort_t*)alloc(nFg * 2);
  ushort_t* w1h = (ushort_t*)alloc(nW1 * 2); ushort_t* w1l = (ushort_t*)alloc(nW1 * 2);
  ushort_t* w2h = (ushort_t*)alloc(nW2 * 2); ushort_t* w2l = (ushort_t*)alloc(nW2 * 2);
  ushort_t* h1h = (ushort_t*)alloc(nH1 * 2); ushort_t* h1l = (ushort_t*)alloc(nH1 * 2);
  ushort_t* w1th = (ushort_t*)alloc((size_t)256 * 128 * 2);
  ushort_t* w1tl = (ushort_t*)alloc((size_t)256 * 128 * 2);
  ushort_t* w2th = (ushort_t*)alloc((size_t)512 * 128 * 2);
  ushort_t* w2tl = (ushort_t*)alloc((size_t)512 * 128 * 2);
  ushort_t* w3th = (ushort_t*)alloc((size_t)512 * 256 * 2);
  ushort_t* w3tl = (ushort_t*)alloc((size_t)512 * 256 * 2);
  ushort_t* w4th = (ushort_t*)alloc((size_t)1024 * 256 * 2);
  ushort_t* w4tl = (ushort_t*)alloc((size_t)1024 * 256 * 2);

  const dim3 blk256(256), blk1024(1024);
  auto mgemm = [&](const ushort_t* Ah, const ushort_t* Al,
                   const ushort_t* Bh, const ushort_t* Bl, const float* bias,
                   int M, int Nn, int K, float* outF) {
    const dim3 grid(Nn / 128, M / 128);
    mfma_gemm_kernel<false, false, false><<<grid, blk256, 0, stream>>>(
        Ah, Al, nullptr, nullptr, nullptr, nullptr, nullptr, nullptr, nullptr,
        nullptr, nullptr, nullptr, nullptr, nullptr, nullptr, nullptr,
        Bh, Bl, bias, K, outF, nullptr, nullptr, Nn);
  };

  // ---- weight prep: single fused dispatch ----
  weight_prep_kernel<<<dim3(6528), blk256, 0, stream>>>(
      w1, w2, w3, w4, cw1, cw2,
      w1th, w1tl, w2th, w2tl, w3th, w3tl, w4th, w4tl,
      w1h, w1l, w2h, w2l);

  // ---- level 0 (4096 verts) ----
  knn_wave_kernel<32, 2048><<<dim3(N0 / 16, B_), blk1024, 0, stream>>>(vertices, N0, N0, nb1);
  conv_surface_kernel<<<dim3(B_ * N0), dim3(128), 0, stream>>>(
      vertices, nb1, dir0, N0, 128, f0h, f0l);
  mgemm(f0h, f0l, w1th, w1tl, b1, B_ * N0, 256, 128, fbuf);
  conv_combine_kernel<<<dim3(B_ * N0), dim3(128), 0, stream>>>(
      fbuf, nb1, d1, vertices, N0, 128, 1, f1h, f1l);

  // ---- pool 1 -> 1024 (top-4 = first 4 of nb1 rows at sidx1) ----
  gather_verts_kernel<<<dim3((B_ * N1 * 3 + 255) / 256), blk256, 0, stream>>>(vertices, sidx1, N0, N1, vp1);
  pool_kernel<<<dim3((B_ * N1 * 128 + 255) / 256), blk256, 0, stream>>>(
      f1h, f1l, nb1, sidx1, N1, N0, 128, p1h, p1l);

  // ---- level 1 (1024 verts) ----
  knn_wave_kernel<32, 1024><<<dim3(N1 / 16, B_), blk1024, 0, stream>>>(vp1, N1, N1, nb2);
  mgemm(p1h, p1l, w2th, w2tl, b2, B_ * N1, 512, 128, fbuf);
  conv_combine_kernel<<<dim3(B_ * N1), dim3(256), 0, stream>>>(
      fbuf, nb2, d2, vp1, N1, 256, 1, f2h, f2l);
  mgemm(f2h, f2l, w3th, w3tl, b3, B_ * N1, 512, 256, fbuf);
  conv_combine_kernel<<<dim3(B_ * N1), dim3(256), 0, stream>>>(
      fbuf, nb2, d3, vp1, N1, 256, 1, f3h, f3l);

  // ---- pool 2 -> 256 ----
  gather_verts_kernel<<<dim3((B_ * N2 * 3 + 255) / 256), blk256, 0, stream>>>(vp1, sidx2, N1, N2, vp2);
  pool_kernel<<<dim3((B_ * N2 * 256 + 255) / 256), blk256, 0, stream>>>(
      f3h, f3l, nb2, sidx2, N2, N1, 256, p2h, p2l);

  // ---- level 2 (256 verts) ----
  knn_wave_kernel<32, 256><<<dim3(N2 / 16, B_), blk1024, 0, stream>>>(vp2, N2, N2, nb3);
  mgemm(p2h, p2l, w4th, w4tl, b4, B_ * N2, 1024, 256, fbuf);
  conv_combine_kernel<<<dim3(B_ * N2), dim3(512), 0, stream>>>(
      fbuf, nb3, d4, vp2, N2, 512, 0, f4h, f4l);     // no relu on fm_4
  global_max_kernel<<<dim3(B_ * 8), blk256, 0, stream>>>(f4h, f4l, fgh, fgl);

  // ---- upsample indices: both levels in one dispatch ----
  nearest_dual_kernel<<<dim3((B_ * N0) / 4, 2), blk256, 0, stream>>>(
      vertices, vp1, vp2, near1, near2);

  // ---- head MLP ----
  mfma_gemm_kernel<true, true, true><<<dim3(512 / 128, (B_ * N0) / 128), blk256, 0, stream>>>(
      nullptr, nullptr,
      f0h, f0l, f1h, f1l, f2h, f2l, f3h, f3l, f4h, f4l, fgh, fgl,
      near1, near2, w1h, w1l, cb1, 1792, nullptr, h1h, h1l, 512);
  mfma_gemm_kernel<false, false, true><<<dim3(512 / 128, (B_ * N0) / 128), blk256, 0, stream>>>(
      h1h, h1l,
      nullptr, nullptr, nullptr, nullptr, nullptr, nullptr, nullptr, nullptr,
      nullptr, nullptr, nullptr, nullptr,
      nullptr, nullptr, w2h, w2l, cb2, 512, h2, nullptr, nullptr, 512);
  head_kernel<<<dim3((B_ * N0 * 13 + 255) / 256), blk256, 0, stream>>>(h2, cw3, cb3, (float*)d_out);
}

// Round 12
// 580.175 us; speedup vs baseline: 1.3031x; 1.1488x over previous
//
#include <hip/hip_runtime.h>
#include <cstdint>
#include <cstddef>

namespace {

typedef unsigned short ushort_t;
typedef __bf16 bf16x8 __attribute__((ext_vector_type(8)));
typedef float  f32x4  __attribute__((ext_vector_type(4)));

constexpr int B_ = 4;
constexpr int N0 = 4096;   // vertices per batch
constexpr int N1 = 1024;   // after pool1
constexpr int N2 = 256;    // after pool2

// ----------------------------------------------------- bf16 split utils ----
__device__ __forceinline__ ushort_t f2bf_rne(float x) {
  uint32_t b = __float_as_uint(x);
  b += 0x7FFFu + ((b >> 16) & 1u);
  return (ushort_t)(b >> 16);
}
__device__ __forceinline__ float bf2f(ushort_t h) {
  return __uint_as_float(((uint32_t)h) << 16);
}
__device__ __forceinline__ void split_store(float x, ushort_t* hi, ushort_t* lo,
                                            size_t i) {
  const ushort_t h = f2bf_rne(x);
  hi[i] = h;
  lo[i] = f2bf_rne(x - bf2f(h));
}

// ------------------- fused prep: weight split/transpose + vp1/vp2 gather ---
// Segments (cumulative): w1t 32768 | w2t 98304 | w3t 229376 | w4t 491520 |
// cw1 1409024 | cw2 1671168 | vp1 1683456 | vp2 1686528
__global__ void prep_kernel(
    const float* __restrict__ w1, const float* __restrict__ w2,
    const float* __restrict__ w3, const float* __restrict__ w4,
    const float* __restrict__ cw1, const float* __restrict__ cw2,
    const float* __restrict__ vertices,
    const int* __restrict__ sidx1, const int* __restrict__ sidx2,
    ushort_t* __restrict__ w1th, ushort_t* __restrict__ w1tl,
    ushort_t* __restrict__ w2th, ushort_t* __restrict__ w2tl,
    ushort_t* __restrict__ w3th, ushort_t* __restrict__ w3tl,
    ushort_t* __restrict__ w4th, ushort_t* __restrict__ w4tl,
    ushort_t* __restrict__ w1h, ushort_t* __restrict__ w1l,
    ushort_t* __restrict__ w2h, ushort_t* __restrict__ w2l,
    float* __restrict__ vp1, float* __restrict__ vp2)
{
  const int i = blockIdx.x * blockDim.x + threadIdx.x;
  if (i < 32768) {                       // w1: K=128, N=256
    const int j = i, k = j % 128, n = j / 128;
    split_store(w1[(size_t)k * 256 + n], w1th, w1tl, (size_t)n * 128 + k);
  } else if (i < 98304) {                // w2: K=128, N=512
    const int j = i - 32768, k = j % 128, n = j / 128;
    split_store(w2[(size_t)k * 512 + n], w2th, w2tl, (size_t)n * 128 + k);
  } else if (i < 229376) {               // w3: K=256, N=512
    const int j = i - 98304, k = j % 256, n = j / 256;
    split_store(w3[(size_t)k * 512 + n], w3th, w3tl, (size_t)n * 256 + k);
  } else if (i < 491520) {               // w4: K=256, N=1024
    const int j = i - 229376, k = j % 256, n = j / 256;
    split_store(w4[(size_t)k * 1024 + n], w4th, w4tl, (size_t)n * 256 + k);
  } else if (i < 1409024) {              // cw1: already (N,K)
    const int j = i - 491520;
    split_store(cw1[j], w1h, w1l, j);
  } else if (i < 1671168) {              // cw2
    const int j = i - 1409024;
    split_store(cw2[j], w2h, w2l, j);
  } else if (i < 1683456) {              // vp1 = vertices[:, sidx1, :]
    const int j = i - 1671168;
    const int c = j % 3, q = (j / 3) % N1, b = j / (3 * N1);
    vp1[j] = vertices[((size_t)b * N0 + sidx1[q]) * 3 + c];
  } else if (i < 1686528) {              // vp2 = vertices[:, sidx1[sidx2], :]
    const int j = i - 1683456;
    const int c = j % 3, q = (j / 3) % N2, b = j / (3 * N2);
    vp2[j] = vertices[((size_t)b * N0 + sidx1[sidx2[q]]) * 3 + c];
  }
}

// ------------------------------------------------- wave-cooperative KNN ----
__device__ __forceinline__ void bitonic_sort64(float& sd, int& si, int lane) {
#pragma unroll
  for (int kk = 2; kk <= 64; kk <<= 1) {
#pragma unroll
    for (int j = kk >> 1; j > 0; j >>= 1) {
      const float od = __shfl_xor(sd, j);
      const int   oi = __shfl_xor(si, j);
      const bool less    = (sd < od) || (sd == od && si < oi);
      const bool wantMin = ((lane & j) == 0) == ((lane & kk) == 0);
      if (wantMin != less) { sd = od; si = oi; }
    }
  }
}

__device__ __forceinline__ void knn_flush(float& ld, int& li, float& tau,
                                          int cnt, const float* bufd,
                                          const int* bufi, int lane, int Km1) {
  float sd = (lane < cnt) ? bufd[lane] : INFINITY;
  int   si = (lane < cnt) ? bufi[lane] : 0x7fffffff;
  bitonic_sort64(sd, si, lane);
  const float rd = __shfl(sd, 63 - lane);
  const int   ri = __shfl(si, 63 - lane);
  const bool keep = (ld < rd) || (ld == rd && li < ri);
  float md = keep ? ld : rd;
  int   mi = keep ? li : ri;
#pragma unroll
  for (int j = 32; j > 0; j >>= 1) {
    const float od = __shfl_xor(md, j);
    const int   oi = __shfl_xor(mi, j);
    const bool less    = (md < od) || (md == od && mi < oi);
    const bool wantMin = ((lane & j) == 0);
    if (wantMin != less) { md = od; mi = oi; }
  }
  ld = md; li = mi;
  tau = __shfl(ld, Km1);
}

// All 3 KNN levels in ONE dispatch. 8 waves/block (round-8 proven config;
// 16-wave round-10 variant regressed: 2 blocks/CU wave cap, occ 42% vs 53%).
// Flat grid: [0,2048) L0 | [2048,2560) L1 | [2560,2688) L2.
// K=32, TILE=2048; levels with C < TILE use partial nt (C % 64 == 0 always).
__launch_bounds__(512)
__global__ void knn_mega_kernel(const float* __restrict__ verts,
                                const float* __restrict__ vp1,
                                const float* __restrict__ vp2,
                                int* __restrict__ nb1,
                                int* __restrict__ nb2,
                                int* __restrict__ nb3)
{
  constexpr int K = 32, TILE = 2048;
  __shared__ float4 sp[TILE];
  __shared__ float sbd[8][64];
  __shared__ int   sbi[8][64];

  int bx = blockIdx.x;
  const float* pts; int Q, C; int* out;
  if (bx < 2048)      { pts = verts; Q = N0; C = N0; out = nb1; }
  else if (bx < 2560) { pts = vp1;   Q = N1; C = N1; out = nb2; bx -= 2048; }
  else                { pts = vp2;   Q = N2; C = N2; out = nb3; bx -= 2560; }
  const int bpb = Q / 8;               // blocks per batch
  const int b  = bx / bpb;
  const int lane = threadIdx.x & 63;
  const int wid  = threadIdx.x >> 6;
  const int q    = (bx % bpb) * 8 + wid;
  const int self = q;
  const float* pb = pts + (size_t)b * C * 3;
  const float qx = pb[self * 3 + 0];
  const float qy = pb[self * 3 + 1];
  const float qz = pb[self * 3 + 2];
  const float q2   = qx * qx + qy * qy + qz * qz;
  const float m2qx = -2.0f * qx, m2qy = -2.0f * qy, m2qz = -2.0f * qz;

  float ld = INFINITY; int li = 0x7fffffff;
  float tau = INFINITY;
  int cnt = 0;
  float* bufd = sbd[wid];
  int*   bufi = sbi[wid];

  auto append = [&](unsigned long long m, bool cand, float d, int ci) {
    const int c = __popcll(m);
    if (cnt + c > 64) {
      knn_flush(ld, li, tau, cnt, bufd, bufi, lane, K - 1);
      cnt = 0;
    }
    const int prefix = __popcll(m & ((1ull << lane) - 1ull));
    if (cand) { bufd[cnt + prefix] = d; bufi[cnt + prefix] = ci; }
    cnt += c;
  };

  for (int t0 = 0; t0 < C; t0 += TILE) {
    const int nt = (C - t0 < TILE) ? (C - t0) : TILE;
    __syncthreads();
    for (int i = threadIdx.x; i < nt; i += 512) {
      const float x = pb[(t0 + i) * 3 + 0];
      const float y = pb[(t0 + i) * 3 + 1];
      const float z = pb[(t0 + i) * 3 + 2];
      sp[i] = make_float4(x, y, z, x * x + y * y + z * z);
    }
    __syncthreads();
    int base = 0;
    if (t0 == 0) {
      // peeled seed batch: bitonic sort of first 64 (stable lowest-index ties)
      const float4 p = sp[lane];
      const float d = fmaf(m2qx, p.x, fmaf(m2qy, p.y, fmaf(m2qz, p.z, p.w + q2)));
      const bool valid = (lane != self);
      float sd = valid ? d : INFINITY;
      int   si = valid ? lane : 0x7fffffff;
      bitonic_sort64(sd, si, lane);
      ld = sd; li = si;
      tau = __shfl(ld, K - 1);
      base = 64;
    }
    for (; base + 128 <= nt; base += 128) {
      const int ci0 = t0 + base + lane;
      const int ci1 = ci0 + 64;
      const float4 p0 = sp[base + lane];
      const float4 p1 = sp[base + 64 + lane];
      const float d0 = fmaf(m2qx, p0.x, fmaf(m2qy, p0.y, fmaf(m2qz, p0.z, p0.w + q2)));
      const float d1 = fmaf(m2qx, p1.x, fmaf(m2qy, p1.y, fmaf(m2qz, p1.z, p1.w + q2)));
      const bool c0 = (ci0 != self) && (d0 < tau);
      const bool c1 = (ci1 != self) && (d1 < tau);
      const unsigned long long m0 = __ballot(c0);
      const unsigned long long m1 = __ballot(c1);
      if (m0) append(m0, c0, d0, ci0);
      if (m1) append(m1, c1, d1, ci1);   // stale-tau entries pruned at flush
    }
    if (base < nt) {                     // single 64-tail (nt % 64 == 0)
      const int ci = t0 + base + lane;
      const float4 p = sp[base + lane];
      const float d = fmaf(m2qx, p.x, fmaf(m2qy, p.y, fmaf(m2qz, p.z, p.w + q2)));
      const bool c = (ci != self) && (d < tau);
      const unsigned long long m = __ballot(c);
      if (m) append(m, c, d, ci);
    }
  }
  if (cnt > 0) knn_flush(ld, li, tau, cnt, bufd, bufi, lane, K - 1);
  if (lane < K) out[((size_t)b * Q + q) * K + lane] = li;
}

// -------------------------------------------- dual-level wave argmin -------
__launch_bounds__(256)
__global__ void nearest_dual_kernel(const float* __restrict__ qpts, // (B*N0,3)
                                    const float* __restrict__ cpts1,
                                    const float* __restrict__ cpts2,
                                    int* __restrict__ out1,
                                    int* __restrict__ out2)
{
  __shared__ float4 sp[1024];
  const int lvl = blockIdx.y;
  const int C = lvl ? N2 : N1;
  const float* cpts = lvl ? cpts2 : cpts1;
  int* out = lvl ? out2 : out1;
  const int lane = threadIdx.x & 63;
  const int wid  = threadIdx.x >> 6;
  const int q    = blockIdx.x * 4 + wid;        // over B_*N0
  const int b    = q >> 12;                     // / 4096
  const float qx = qpts[(size_t)q * 3 + 0];
  const float qy = qpts[(size_t)q * 3 + 1];
  const float qz = qpts[(size_t)q * 3 + 2];
  const float q2   = qx * qx + qy * qy + qz * qz;
  const float m2qx = -2.0f * qx, m2qy = -2.0f * qy, m2qz = -2.0f * qz;
  const float* pb = cpts + (size_t)b * C * 3;

  for (int i = threadIdx.x; i < C; i += 256) {
    const float x = pb[i * 3 + 0];
    const float y = pb[i * 3 + 1];
    const float z = pb[i * 3 + 2];
    sp[i] = make_float4(x, y, z, x * x + y * y + z * z);
  }
  __syncthreads();
  float best = INFINITY; int bi = 0x7fffffff;
  for (int base = 0; base < C; base += 64) {
    const float4 p = sp[base + lane];
    const float d = fmaf(m2qx, p.x, fmaf(m2qy, p.y, fmaf(m2qz, p.z, p.w + q2)));
    if (d < best) { best = d; bi = base + lane; }
  }
#pragma unroll
  for (int j = 1; j < 64; j <<= 1) {
    const float od = __shfl_xor(best, j);
    const int   oi = __shfl_xor(bi, j);
    if (od < best || (od == best && oi < bi)) { best = od; bi = oi; }
  }
  if (lane == 0) out[q] = bi;
}

// -------------------------------------------------------- conv_surface -----
__global__ void conv_surface_kernel(const float* __restrict__ verts,
                                    const int*   __restrict__ nb,
                                    const float* __restrict__ dir,
                                    int V, int C,
                                    ushort_t* __restrict__ outH,
                                    ushort_t* __restrict__ outL) {
  __shared__ float ux[32], uy[32], uz[32];
  const int bv = blockIdx.x;
  const int b = bv / V;
  const int v = bv - b * V;
  const float* vb = verts + (size_t)b * V * 3;
  if (threadIdx.x < 32) {
    const float cx = vb[v * 3 + 0], cy = vb[v * 3 + 1], cz = vb[v * 3 + 2];
    const int nidx = nb[(size_t)bv * 32 + threadIdx.x];
    const float dx = vb[nidx * 3 + 0] - cx;
    const float dy = vb[nidx * 3 + 1] - cy;
    const float dz = vb[nidx * 3 + 2] - cz;
    const float rn = 1.0f / fmaxf(sqrtf(dx * dx + dy * dy + dz * dz), 1e-12f);
    ux[threadIdx.x] = dx * rn; uy[threadIdx.x] = dy * rn; uz[threadIdx.x] = dz * rn;
  }
  __syncthreads();
  const int o = threadIdx.x;
  float d0 = dir[o], d1 = dir[C + o], d2 = dir[2 * C + o];
  const float rn = 1.0f / fmaxf(sqrtf(d0 * d0 + d1 * d1 + d2 * d2), 1e-12f);
  d0 *= rn; d1 *= rn; d2 *= rn;
  float m = -INFINITY;
#pragma unroll
  for (int n = 0; n < 32; ++n) {
    const float t = fmaxf(0.0f, fmaf(d2, uz[n], fmaf(d1, uy[n], d0 * ux[n])));
    m = fmaxf(m, t);
  }
  split_store(fmaxf(0.0f, m), outH, outL, (size_t)bv * C + o);
}

// -------------------------------------------------------- conv_combine -----
__global__ void conv_combine_kernel(const float* __restrict__ f,    // (B,V,2C)
                                    const int*   __restrict__ nb,
                                    const float* __restrict__ dir,
                                    const float* __restrict__ verts,
                                    int V, int C, int relu,
                                    ushort_t* __restrict__ outH,
                                    ushort_t* __restrict__ outL) {
  __shared__ float ux[32], uy[32], uz[32];
  __shared__ int snb[32];
  const int bv = blockIdx.x;
  const int b = bv / V;
  const int v = bv - b * V;
  const float* vb = verts + (size_t)b * V * 3;
  if (threadIdx.x < 32) {
    const float cx = vb[v * 3 + 0], cy = vb[v * 3 + 1], cz = vb[v * 3 + 2];
    const int nidx = nb[(size_t)bv * 32 + threadIdx.x];
    snb[threadIdx.x] = nidx;
    const float dx = vb[nidx * 3 + 0] - cx;
    const float dy = vb[nidx * 3 + 1] - cy;
    const float dz = vb[nidx * 3 + 2] - cz;
    const float rn = 1.0f / fmaxf(sqrtf(dx * dx + dy * dy + dz * dz), 1e-12f);
    ux[threadIdx.x] = dx * rn; uy[threadIdx.x] = dy * rn; uz[threadIdx.x] = dz * rn;
  }
  __syncthreads();
  const int o = threadIdx.x;
  float d0 = dir[o], d1 = dir[C + o], d2 = dir[2 * C + o];
  const float rn = 1.0f / fmaxf(sqrtf(d0 * d0 + d1 * d1 + d2 * d2), 1e-12f);
  d0 *= rn; d1 *= rn; d2 *= rn;
  const float* fb = f + (size_t)b * V * 2 * C;
  float m = -INFINITY;
#pragma unroll 8
  for (int n = 0; n < 32; ++n) {
    const float t = fmaxf(0.0f, fmaf(d2, uz[n], fmaf(d1, uy[n], d0 * ux[n])));
    const float s = fb[(size_t)snb[n] * 2 * C + C + o];
    m = fmaxf(m, t * s);
  }
  float r = fb[(size_t)v * 2 * C + o] + m;
  if (relu) r = fmaxf(r, 0.0f);
  split_store(r, outH, outL, (size_t)bv * C + o);
}

// ---------------------------------------------------------------- pool -----
__global__ void pool_kernel(const ushort_t* __restrict__ fmH,
                            const ushort_t* __restrict__ fmL,
                            const int*   __restrict__ nb,   // (B, Vsrc, 32)
                            const int*   __restrict__ sidx, // (Q,)
                            int Q, int Vsrc, int C,
                            ushort_t* __restrict__ outH,
                            ushort_t* __restrict__ outL) {
  const int i = blockIdx.x * blockDim.x + threadIdx.x;
  if (i >= B_ * Q * C) return;
  const int c = i % C;
  const int q = (i / C) % Q;
  const int b = i / (C * Q);
  const int* nn = nb + ((size_t)b * Vsrc + sidx[q]) * 32;
  const size_t fb = (size_t)b * Vsrc * C;
  float m = -INFINITY;
#pragma unroll
  for (int t = 0; t < 4; ++t) {
    const size_t idx = fb + (size_t)nn[t] * C + c;
    m = fmaxf(m, bf2f(fmH[idx]) + bf2f(fmL[idx]));
  }
  split_store(m, outH, outL, (size_t)i);
}

// grid = B_*8 blocks of 256 thr: 64 channels x 4 v-slices per block
__global__ void global_max_kernel(const ushort_t* __restrict__ fmH,
                                  const ushort_t* __restrict__ fmL,
                                  ushort_t* __restrict__ outH,
                                  ushort_t* __restrict__ outL) {
  __shared__ float red[4][64];
  const int t = threadIdx.x;
  const int cl = t & 63, slice = t >> 6;
  const int c = (blockIdx.x & 7) * 64 + cl;
  const int b = blockIdx.x >> 3;
  const size_t base = (size_t)b * 256 * 512 + c;
  float m = -INFINITY;
  for (int v = slice; v < 256; v += 4) {
    const size_t idx = base + (size_t)v * 512;
    m = fmaxf(m, bf2f(fmH[idx]) + bf2f(fmL[idx]));
  }
  red[slice][cl] = m;
  __syncthreads();
  if (slice == 0) {
    m = fmaxf(fmaxf(red[0][cl], red[1][cl]), fmaxf(red[2][cl], red[3][cl]));
    split_store(m, outH, outL, (size_t)b * 512 + c);
  }
}

// ------------------------------------------- split-bf16 MFMA GEMM ----------
// Round-8 staging (VGPR+ds_write, thread-pair 32B-contiguous loads) — the
// global_load_lds variant (round 9) regressed at this 2-block/CU occupancy.
constexpr int LDT = 40;  // LDS row stride in ushorts (32 + 8 pad)

template<bool FUSE, bool SPLITOUT, bool RELU>
__launch_bounds__(256)
__global__ void mfma_gemm_kernel(
    const ushort_t* __restrict__ Ahi, const ushort_t* __restrict__ Alo,
    const ushort_t* __restrict__ f0h, const ushort_t* __restrict__ f0l,
    const ushort_t* __restrict__ f1h, const ushort_t* __restrict__ f1l,
    const ushort_t* __restrict__ f2h, const ushort_t* __restrict__ f2l,
    const ushort_t* __restrict__ f3h, const ushort_t* __restrict__ f3l,
    const ushort_t* __restrict__ f4h, const ushort_t* __restrict__ f4l,
    const ushort_t* __restrict__ fgh, const ushort_t* __restrict__ fgl,
    const int* __restrict__ near1, const int* __restrict__ near2,
    const ushort_t* __restrict__ Bhi, const ushort_t* __restrict__ Blo,
    const float* __restrict__ bias, int K,
    float* __restrict__ outF, ushort_t* __restrict__ outHi,
    ushort_t* __restrict__ outLo, int Nn)
{
  __shared__ ushort_t As_h[128 * LDT];
  __shared__ ushort_t As_l[128 * LDT];
  __shared__ ushort_t Bs_h[128 * LDT];
  __shared__ ushort_t Bs_l[128 * LDT];

  const int tid  = threadIdx.x;
  const int lane = tid & 63;
  const int wv   = tid >> 6;
  const int wr   = wv >> 1, wc = wv & 1;
  const int quad = lane >> 4, ml = lane & 15;
  const int m0 = blockIdx.y * 128, n0 = blockIdx.x * 128;

  const int r  = tid >> 1;         // staging row 0..127
  const int hh = (tid & 1) * 16;   // 16-elem half of BK=32

  int fb = 0, r1 = 0, r2 = 0;
  if (FUSE) {
    const int m = m0 + r;
    fb = m >> 12;                  // / 4096
    r1 = near1[m];
    r2 = near2[m];
  }

  f32x4 acc[4][4];
#pragma unroll
  for (int i = 0; i < 4; ++i)
#pragma unroll
    for (int j = 0; j < 4; ++j) acc[i][j] = f32x4{0.f, 0.f, 0.f, 0.f};

  for (int k0 = 0; k0 < K; k0 += 32) {
    const int k = k0 + hh;
    uint4 a0h, a1h, a0l, a1l;
    {
      const ushort_t *sh, *sl; size_t off;
      if (FUSE) {
        const int m = m0 + r;
        if (k < 128)       { sh = f0h; sl = f0l; off = (size_t)m * 128 + k; }
        else if (k < 256)  { sh = f1h; sl = f1l; off = (size_t)m * 128 + (k - 128); }
        else if (k < 512)  { sh = f2h; sl = f2l; off = ((size_t)fb * 1024 + r1) * 256 + (k - 256); }
        else if (k < 768)  { sh = f3h; sl = f3l; off = ((size_t)fb * 1024 + r1) * 256 + (k - 512); }
        else if (k < 1280) { sh = f4h; sl = f4l; off = ((size_t)fb * 256 + r2) * 512 + (k - 768); }
        else               { sh = fgh; sl = fgl; off = (size_t)fb * 512 + (k - 1280); }
      } else {
        sh = Ahi; sl = Alo; off = (size_t)(m0 + r) * K + k;
      }
      a0h = *(const uint4*)(sh + off); a1h = *(const uint4*)(sh + off + 8);
      a0l = *(const uint4*)(sl + off); a1l = *(const uint4*)(sl + off + 8);
    }
    uint4 b0h, b1h, b0l, b1l;
    {
      const size_t off = (size_t)(n0 + r) * K + k;
      b0h = *(const uint4*)(Bhi + off); b1h = *(const uint4*)(Bhi + off + 8);
      b0l = *(const uint4*)(Blo + off); b1l = *(const uint4*)(Blo + off + 8);
    }
    __syncthreads();   // previous iteration's fragment reads complete
    *(uint4*)&As_h[r * LDT + hh]     = a0h;
    *(uint4*)&As_h[r * LDT + hh + 8] = a1h;
    *(uint4*)&As_l[r * LDT + hh]     = a0l;
    *(uint4*)&As_l[r * LDT + hh + 8] = a1l;
    *(uint4*)&Bs_h[r * LDT + hh]     = b0h;
    *(uint4*)&Bs_h[r * LDT + hh + 8] = b1h;
    *(uint4*)&Bs_l[r * LDT + hh]     = b0l;
    *(uint4*)&Bs_l[r * LDT + hh + 8] = b1l;
    __syncthreads();

    bf16x8 ah[4], al[4], bh[4], bl[4];
#pragma unroll
    for (int i = 0; i < 4; ++i) {
      const int row = wr * 64 + i * 16 + ml;
      ah[i] = *(const bf16x8*)&As_h[row * LDT + quad * 8];
      al[i] = *(const bf16x8*)&As_l[row * LDT + quad * 8];
    }
#pragma unroll
    for (int j = 0; j < 4; ++j) {
      const int row = wc * 64 + j * 16 + ml;
      bh[j] = *(const bf16x8*)&Bs_h[row * LDT + quad * 8];
      bl[j] = *(const bf16x8*)&Bs_l[row * LDT + quad * 8];
    }
#pragma unroll
    for (int i = 0; i < 4; ++i)
#pragma unroll
      for (int j = 0; j < 4; ++j) {
        acc[i][j] = __builtin_amdgcn_mfma_f32_16x16x32_bf16(al[i], bh[j], acc[i][j], 0, 0, 0);
        acc[i][j] = __builtin_amdgcn_mfma_f32_16x16x32_bf16(ah[i], bl[j], acc[i][j], 0, 0, 0);
        acc[i][j] = __builtin_amdgcn_mfma_f32_16x16x32_bf16(ah[i], bh[j], acc[i][j], 0, 0, 0);
      }
  }

  // epilogue: C/D mapping col=lane&15, row=quad*4+reg (m89)
#pragma unroll
  for (int i = 0; i < 4; ++i)
#pragma unroll
    for (int j = 0; j < 4; ++j) {
      const int n = n0 + wc * 64 + j * 16 + ml;
      const float bv = bias[n];
#pragma unroll
      for (int reg = 0; reg < 4; ++reg) {
        const int m = m0 + wr * 64 + i * 16 + quad * 4 + reg;
        float r = acc[i][j][reg] + bv;
        if (RELU) r = fmaxf(r, 0.0f);
        if (SPLITOUT) {
          const ushort_t h = f2bf_rne(r);
          outHi[(size_t)m * Nn + n] = h;
          outLo[(size_t)m * Nn + n] = f2bf_rne(r - bf2f(h));
        } else {
          outF[(size_t)m * Nn + n] = r;
        }
      }
    }
}

// --------------------------------------------------- head: wave per row ----
// One wave per output row; h row read exactly once (8 f32/lane), cw3/cb3
// staged in LDS; 13 shfl-reduced dot products.
__launch_bounds__(256)
__global__ void head_wave_kernel(const float* __restrict__ h,   // (16384, 512)
                                 const float* __restrict__ cw,  // (13, 512)
                                 const float* __restrict__ cb,  // (13,)
                                 float* __restrict__ out) {     // (16384, 13)
  __shared__ float ws[13 * 512];
  __shared__ float cbs[13];
  const int lane = threadIdx.x & 63;
  const int wid  = threadIdx.x >> 6;
  for (int i = threadIdx.x; i < 13 * 512; i += 256) ws[i] = cw[i];
  if (threadIdx.x < 13) cbs[threadIdx.x] = cb[threadIdx.x];
  __syncthreads();
  const int row = blockIdx.x * 4 + wid;
  const float4* hr = (const float4*)(h + (size_t)row * 512);
  const float4 a0 = hr[lane * 2], a1 = hr[lane * 2 + 1];
#pragma unroll
  for (int o = 0; o < 13; ++o) {
    const float4* wr = (const float4*)(ws + o * 512);
    const float4 w0 = wr[lane * 2], w1 = wr[lane * 2 + 1];
    float p = a0.x * w0.x + a0.y * w0.y + a0.z * w0.z + a0.w * w0.w
            + a1.x * w1.x + a1.y * w1.y + a1.z * w1.z + a1.w * w1.w;
#pragma unroll
    for (int j = 1; j < 64; j <<= 1) p += __shfl_xor(p, j);
    if (lane == 0) out[(size_t)row * 13 + o] = p + cbs[o];
  }
}

} // namespace

extern "C" void kernel_launch(void* const* d_in, const int* in_sizes, int n_in,
                              void* d_out, int out_size, void* d_ws, size_t ws_size,
                              hipStream_t stream)
{
  const float* vertices = (const float*)d_in[0];
  const int*   sidx1    = (const int*)  d_in[1];
  const int*   sidx2    = (const int*)  d_in[2];
  const float* dir0     = (const float*)d_in[3];
  const float* w1 = (const float*)d_in[4];
  const float* b1 = (const float*)d_in[5];
  const float* d1 = (const float*)d_in[6];
  const float* w2 = (const float*)d_in[7];
  const float* b2 = (const float*)d_in[8];
  const float* d2 = (const float*)d_in[9];
  const float* w3 = (const float*)d_in[10];
  const float* b3 = (const float*)d_in[11];
  const float* d3 = (const float*)d_in[12];
  const float* w4 = (const float*)d_in[13];
  const float* b4 = (const float*)d_in[14];
  const float* d4 = (const float*)d_in[15];
  const float* cw1 = (const float*)d_in[16];
  const float* cb1 = (const float*)d_in[17];
  const float* cw2 = (const float*)d_in[18];
  const float* cb2 = (const float*)d_in[19];
  const float* cw3 = (const float*)d_in[20];
  const float* cb3 = (const float*)d_in[21];
  (void)in_sizes; (void)n_in; (void)out_size; (void)ws_size;

  char* ws = (char*)d_ws;
  size_t off = 0;
  auto alloc = [&](size_t bytes) -> void* {
    void* p = ws + off;
    off += (bytes + 255) & ~(size_t)255;
    return p;
  };

  int*   nb1   = (int*)  alloc((size_t)B_ * N0 * 32 * 4);
  int*   nb2   = (int*)  alloc((size_t)B_ * N1 * 32 * 4);
  int*   nb3   = (int*)  alloc((size_t)B_ * N2 * 32 * 4);
  float* vp1   = (float*)alloc((size_t)B_ * N1 * 3 * 4);
  float* vp2   = (float*)alloc((size_t)B_ * N2 * 3 * 4);
  int*   near1 = (int*)  alloc((size_t)B_ * N0 * 4);
  int*   near2 = (int*)  alloc((size_t)B_ * N0 * 4);
  float* h2    = (float*)alloc((size_t)B_ * N0 * 512 * 4);   // 32 MB
  float* fbuf  = (float*)alloc((size_t)B_ * N0 * 256 * 4);   // 16 MB

  const size_t nF0 = (size_t)B_ * N0 * 128;   // fm0 / fm1
  const size_t nP1 = (size_t)B_ * N1 * 128;   // fmp1
  const size_t nF2 = (size_t)B_ * N1 * 256;   // fm2 / fm3
  const size_t nP2 = (size_t)B_ * N2 * 256;   // fmp2
  const size_t nF4 = (size_t)B_ * N2 * 512;
  const size_t nFg = (size_t)B_ * 512;
  const size_t nW1 = (size_t)512 * 1792;
  const size_t nW2 = (size_t)512 * 512;
  const size_t nH1 = (size_t)B_ * N0 * 512;
  ushort_t* f0h = (ushort_t*)alloc(nF0 * 2); ushort_t* f0l = (ushort_t*)alloc(nF0 * 2);
  ushort_t* f1h = (ushort_t*)alloc(nF0 * 2); ushort_t* f1l = (ushort_t*)alloc(nF0 * 2);
  ushort_t* p1h = (ushort_t*)alloc(nP1 * 2); ushort_t* p1l = (ushort_t*)alloc(nP1 * 2);
  ushort_t* f2h = (ushort_t*)alloc(nF2 * 2); ushort_t* f2l = (ushort_t*)alloc(nF2 * 2);
  ushort_t* f3h = (ushort_t*)alloc(nF2 * 2); ushort_t* f3l = (ushort_t*)alloc(nF2 * 2);
  ushort_t* p2h = (ushort_t*)alloc(nP2 * 2); ushort_t* p2l = (ushort_t*)alloc(nP2 * 2);
  ushort_t* f4h = (ushort_t*)alloc(nF4 * 2); ushort_t* f4l = (ushort_t*)alloc(nF4 * 2);
  ushort_t* fgh = (ushort_t*)alloc(nFg * 2); ushort_t* fgl = (ushort_t*)alloc(nFg * 2);
  ushort_t* w1h = (ushort_t*)alloc(nW1 * 2); ushort_t* w1l = (ushort_t*)alloc(nW1 * 2);
  ushort_t* w2h = (ushort_t*)alloc(nW2 * 2); ushort_t* w2l = (ushort_t*)alloc(nW2 * 2);
  ushort_t* h1h = (ushort_t*)alloc(nH1 * 2); ushort_t* h1l = (ushort_t*)alloc(nH1 * 2);
  ushort_t* w1th = (ushort_t*)alloc((size_t)256 * 128 * 2);
  ushort_t* w1tl = (ushort_t*)alloc((size_t)256 * 128 * 2);
  ushort_t* w2th = (ushort_t*)alloc((size_t)512 * 128 * 2);
  ushort_t* w2tl = (ushort_t*)alloc((size_t)512 * 128 * 2);
  ushort_t* w3th = (ushort_t*)alloc((size_t)512 * 256 * 2);
  ushort_t* w3tl = (ushort_t*)alloc((size_t)512 * 256 * 2);
  ushort_t* w4th = (ushort_t*)alloc((size_t)1024 * 256 * 2);
  ushort_t* w4tl = (ushort_t*)alloc((size_t)1024 * 256 * 2);

  const dim3 blk256(256), blk512(512);
  auto mgemm = [&](const ushort_t* Ah, const ushort_t* Al,
                   const ushort_t* Bh, const ushort_t* Bl, const float* bias,
                   int M, int Nn, int K, float* outF) {
    const dim3 grid(Nn / 128, M / 128);
    mfma_gemm_kernel<false, false, false><<<grid, blk256, 0, stream>>>(
        Ah, Al, nullptr, nullptr, nullptr, nullptr, nullptr, nullptr, nullptr,
        nullptr, nullptr, nullptr, nullptr, nullptr, nullptr, nullptr,
        Bh, Bl, bias, K, outF, nullptr, nullptr, Nn);
  };

  // ---- prep: weights + vp1/vp2 in one dispatch ----
  prep_kernel<<<dim3(6588), blk256, 0, stream>>>(
      w1, w2, w3, w4, cw1, cw2, vertices, sidx1, sidx2,
      w1th, w1tl, w2th, w2tl, w3th, w3tl, w4th, w4tl,
      w1h, w1l, w2h, w2l, vp1, vp2);

  // ---- all three KNN levels, one dispatch ----
  knn_mega_kernel<<<dim3(2688), blk512, 0, stream>>>(
      vertices, vp1, vp2, nb1, nb2, nb3);

  // ---- level 0 (4096 verts) ----
  conv_surface_kernel<<<dim3(B_ * N0), dim3(128), 0, stream>>>(
      vertices, nb1, dir0, N0, 128, f0h, f0l);
  mgemm(f0h, f0l, w1th, w1tl, b1, B_ * N0, 256, 128, fbuf);
  conv_combine_kernel<<<dim3(B_ * N0), dim3(128), 0, stream>>>(
      fbuf, nb1, d1, vertices, N0, 128, 1, f1h, f1l);

  // ---- pool 1 -> 1024 (top-4 = first 4 of nb1 rows at sidx1) ----
  pool_kernel<<<dim3((B_ * N1 * 128 + 255) / 256), blk256, 0, stream>>>(
      f1h, f1l, nb1, sidx1, N1, N0, 128, p1h, p1l);

  // ---- level 1 (1024 verts) ----
  mgemm(p1h, p1l, w2th, w2tl, b2, B_ * N1, 512, 128, fbuf);
  conv_combine_kernel<<<dim3(B_ * N1), dim3(256), 0, stream>>>(
      fbuf, nb2, d2, vp1, N1, 256, 1, f2h, f2l);
  mgemm(f2h, f2l, w3th, w3tl, b3, B_ * N1, 512, 256, fbuf);
  conv_combine_kernel<<<dim3(B_ * N1), dim3(256), 0, stream>>>(
      fbuf, nb2, d3, vp1, N1, 256, 1, f3h, f3l);

  // ---- pool 2 -> 256 ----
  pool_kernel<<<dim3((B_ * N2 * 256 + 255) / 256), blk256, 0, stream>>>(
      f3h, f3l, nb2, sidx2, N2, N1, 256, p2h, p2l);

  // ---- level 2 (256 verts) ----
  mgemm(p2h, p2l, w4th, w4tl, b4, B_ * N2, 1024, 256, fbuf);
  conv_combine_kernel<<<dim3(B_ * N2), dim3(512), 0, stream>>>(
      fbuf, nb3, d4, vp2, N2, 512, 0, f4h, f4l);     // no relu on fm_4
  global_max_kernel<<<dim3(B_ * 8), blk256, 0, stream>>>(f4h, f4l, fgh, fgl);

  // ---- upsample indices: both levels in one dispatch ----
  nearest_dual_kernel<<<dim3((B_ * N0) / 4, 2), blk256, 0, stream>>>(
      vertices, vp1, vp2, near1, near2);

  // ---- head MLP ----
  mfma_gemm_kernel<true, true, true><<<dim3(512 / 128, (B_ * N0) / 128), blk256, 0, stream>>>(
      nullptr, nullptr,
      f0h, f0l, f1h, f1l, f2h, f2l, f3h, f3l, f4h, f4l, fgh, fgl,
      near1, near2, w1h, w1l, cb1, 1792, nullptr, h1h, h1l, 512);
  mfma_gemm_kernel<false, false, true><<<dim3(512 / 128, (B_ * N0) / 128), blk256, 0, stream>>>(
      h1h, h1l,
      nullptr, nullptr, nullptr, nullptr, nullptr, nullptr, nullptr, nullptr,
      nullptr, nullptr, nullptr, nullptr,
      nullptr, nullptr, w2h, w2l, cb2, 512, h2, nullptr, nullptr, 512);
  head_wave_kernel<<<dim3((B_ * N0) / 4), blk256, 0, stream>>>(
      h2, cw3, cb3, (float*)d_out);
}